// Round 4
// baseline (182.260 us; speedup 1.0000x reference)
//
#include <hip/hip_runtime.h>
#include <math.h>

// B,S,E,H = 4,2048,1024,128
#define BB 4
#define SS 2048
#define EE 1024
#define HH 128
#define PLANE (BB * SS * HH)   // per-plane elems
#define BPLANE (SS * HH)       // per-batch elems
#define UNITS_PB 320           // sum over 128 subtiles of ceil((s+1)/32)

typedef __bf16 bf16x8 __attribute__((ext_vector_type(8)));
typedef __bf16 bf16x4 __attribute__((ext_vector_type(4)));
typedef float f32x4 __attribute__((ext_vector_type(4)));

#define QSCALE (0.08838834764831845f * 1.4426950408889634f)  // 1/sqrt(H)*log2e

// ---------------------------------------------------------------------------
// Kernel 0: W -> WT bf16 transpose. WT[p][n][k]. Grid 384 blocks (p x 32 ktile
// x 4 ntile), each transposes a 32k x 32n tile through LDS.
// ---------------------------------------------------------------------------
__global__ __launch_bounds__(256) void prep_w(
    const float* __restrict__ Wq, const float* __restrict__ Wk,
    const float* __restrict__ Wv, __bf16* __restrict__ WT) {
  __shared__ float LT[32 * 33];
  const int p = blockIdx.x >> 7;
  const int r = blockIdx.x & 127;
  const int kb = (r >> 2) * 32, nb = (r & 3) * 32;
  const float* __restrict__ W = (p == 0) ? Wq : (p == 1) ? Wk : Wv;
  const int t = threadIdx.x;
  const int kr = t >> 3, nc4 = (t & 7) * 4;
  const float4 v = *(const float4*)&W[(size_t)(kb + kr) * HH + nb + nc4];
  LT[(nc4 + 0) * 33 + kr] = v.x;
  LT[(nc4 + 1) * 33 + kr] = v.y;
  LT[(nc4 + 2) * 33 + kr] = v.z;
  LT[(nc4 + 3) * 33 + kr] = v.w;
  __syncthreads();
  const int n = t >> 3, kc = (t & 7) * 4;
  bf16x4 o;
#pragma unroll
  for (int i = 0; i < 4; ++i) o[i] = (__bf16)LT[n * 33 + kc + i];
  *(bf16x4*)&WT[(size_t)p * (HH * EE) + (size_t)(nb + n) * EE + kb + kc] = o;
}

// ---------------------------------------------------------------------------
// Kernel 1: QKV projection. Grid 256 blocks; block = 32 rows x ALL 384 cols
// (q|k|v), BK=64 double-buffered (1 barrier/step, 16 steps). 4 waves = 4
// col-quarters (96 cols, 6 B-frags) x 32 rows (2 A-frags). x staged fp32->bf16
// in LDS once per block; W B-frags direct from global WT (L2-hot, 0.75 MB).
// q scaled by QSCALE; v written transposed vT[b][d][s].
// ---------------------------------------------------------------------------
__global__ __launch_bounds__(256) void qkv_proj(
    const float* __restrict__ x, const __bf16* __restrict__ WT,
    __bf16* __restrict__ qkv) {
  __shared__ __align__(16) __bf16 xs[2][32 * 72];  // 32 rows x 64 k, stride 72

  const int t = threadIdx.x, w = t >> 6, lane = t & 63;
  const int quad = lane >> 4, l16 = lane & 15;
  const int mb = blockIdx.x * 32;

  // staging coords: 2 float4 per thread covering 32x64 fp32
  const int row0 = t >> 4, kc0 = (t & 15) * 4;          // it=0
  const int row1 = (t + 256) >> 4, kc1 = kc0;           // it=1

  f32x4 acc[2][6];
#pragma unroll
  for (int i = 0; i < 2; ++i)
#pragma unroll
    for (int j = 0; j < 6; ++j) acc[i][j] = (f32x4){0.f, 0.f, 0.f, 0.f};

  // prologue: stage tile 0
  {
    const float4 a = *(const float4*)&x[(size_t)(mb + row0) * EE + kc0];
    const float4 b = *(const float4*)&x[(size_t)(mb + row1) * EE + kc1];
    bf16x4 ba, bb;
    ba[0] = (__bf16)a.x; ba[1] = (__bf16)a.y; ba[2] = (__bf16)a.z; ba[3] = (__bf16)a.w;
    bb[0] = (__bf16)b.x; bb[1] = (__bf16)b.y; bb[2] = (__bf16)b.z; bb[3] = (__bf16)b.w;
    *(bf16x4*)&xs[0][row0 * 72 + kc0] = ba;
    *(bf16x4*)&xs[0][row1 * 72 + kc1] = bb;
  }
  __syncthreads();

  for (int kt = 0; kt < 16; ++kt) {
    const int cur = kt & 1;
    float4 pf0, pf1;
    if (kt < 15) {
      pf0 = *(const float4*)&x[(size_t)(mb + row0) * EE + (kt + 1) * 64 + kc0];
      pf1 = *(const float4*)&x[(size_t)(mb + row1) * EE + (kt + 1) * 64 + kc1];
    }
    bf16x8 af[2][2];
#pragma unroll
    for (int rs = 0; rs < 2; ++rs)
#pragma unroll
      for (int kci = 0; kci < 2; ++kci)
        af[rs][kci] =
            *(const bf16x8*)&xs[cur][(rs * 16 + l16) * 72 + kci * 32 + quad * 8];
#pragma unroll
    for (int j = 0; j < 6; ++j) {
      const int c0 = w * 96 + j * 16;
      const int p = c0 >> 7, n0 = c0 & 127;
      const __bf16* bp =
          WT + (size_t)p * (HH * EE) + (size_t)(n0 + l16) * EE + kt * 64 + quad * 8;
#pragma unroll
      for (int kci = 0; kci < 2; ++kci) {
        const bf16x8 bfr = *(const bf16x8*)(bp + kci * 32);
#pragma unroll
        for (int rs = 0; rs < 2; ++rs)
          acc[rs][j] = __builtin_amdgcn_mfma_f32_16x16x32_bf16(
              af[rs][kci], bfr, acc[rs][j], 0, 0, 0);
      }
    }
    if (kt < 15) {
      bf16x4 ba, bb;
      ba[0] = (__bf16)pf0.x; ba[1] = (__bf16)pf0.y; ba[2] = (__bf16)pf0.z; ba[3] = (__bf16)pf0.w;
      bb[0] = (__bf16)pf1.x; bb[1] = (__bf16)pf1.y; bb[2] = (__bf16)pf1.z; bb[3] = (__bf16)pf1.w;
      *(bf16x4*)&xs[cur ^ 1][row0 * 72 + kc0] = ba;
      *(bf16x4*)&xs[cur ^ 1][row1 * 72 + kc1] = bb;
    }
    __syncthreads();
  }

#pragma unroll
  for (int rs = 0; rs < 2; ++rs) {
    const int s0 = mb + rs * 16 + quad * 4;
#pragma unroll
    for (int j = 0; j < 6; ++j) {
      const int c0 = w * 96 + j * 16;
      const int p = c0 >> 7, n0 = c0 & 127;
      if (p < 2) {
        const float scale = (p == 0) ? QSCALE : 1.0f;
        __bf16* outp = qkv + (size_t)p * PLANE;
#pragma unroll
        for (int rr = 0; rr < 4; ++rr)
          outp[(size_t)(s0 + rr) * HH + n0 + l16] = (__bf16)(acc[rs][j][rr] * scale);
      } else {
        const int b = s0 >> 11, sl = s0 & 2047;
        const int d = n0 + l16;
        bf16x4 vv;
#pragma unroll
        for (int rr = 0; rr < 4; ++rr) vv[rr] = (__bf16)acc[rs][j][rr];
        *(bf16x4*)&qkv[2 * (size_t)PLANE + (size_t)b * BPLANE + (size_t)d * SS + sl] = vv;
      }
    }
  }
}

// ---------------------------------------------------------------------------
// Kernel 2: causal attention. Block-unit = (b, 16 q-rows, 512-k chunk); the 4
// waves each take 128 k (<=4 steps of 32) and merge IN-BLOCK via LDS.
// Grid 1280 blocks (5/CU, 20 waves/CU). Units with s<32 (single chunk) write
// normalized fp32 out directly; others write bf16 partials + l for attn_merge.
// Heavy units launched first (reversed index).
// ---------------------------------------------------------------------------
__global__ __launch_bounds__(256) void flash_attn_mfma(
    const __bf16* __restrict__ qkv, float* __restrict__ out,
    __bf16* __restrict__ Opart, float* __restrict__ lpart) {
  __shared__ __align__(16) __bf16 P_s[4][16 * 40];
  __shared__ __align__(16) float mbuf[3 * 2048];
  __shared__ float l_buf[3][16];

  const int t = threadIdx.x, w = t >> 6, lane = t & 63;
  const int quad = lane >> 4, l16 = lane & 15;
  const int b = blockIdx.x & 3;
  const int r = (UNITS_PB - 1) - (blockIdx.x >> 2);  // heavy-first
  int gb = 0;
  while (16 * (gb + 1) * (gb + 2) <= r) ++gb;        // gb = s>>5
  const int rem = r - 16 * gb * (gb + 1);
  const int ncb = gb + 1;
  const int sloc = rem / ncb, cb = rem % ncb;
  const int s = 32 * gb + sloc;
  const int qrb = s * 16;
  const int k0 = cb * 512 + w * 128;
  const int kend = min(k0 + 128, qrb + 16);

  const size_t bq = (size_t)b * BPLANE;
  const __bf16* __restrict__ qp = qkv + bq;
  const __bf16* __restrict__ kp = qkv + PLANE + bq;
  const __bf16* __restrict__ vt = qkv + 2 * (size_t)PLANE + bq;  // [d][s]

  bf16x8 qf[4];
#pragma unroll
  for (int cc = 0; cc < 4; ++cc)
    qf[cc] = *(const bf16x8*)&qp[(size_t)(qrb + l16) * HH + cc * 32 + quad * 8];

  f32x4 of[8];
#pragma unroll
  for (int f = 0; f < 8; ++f) of[f] = (f32x4){0.f, 0.f, 0.f, 0.f};
  float lp[4] = {0.f, 0.f, 0.f, 0.f};

  for (int kk = k0; kk < kend; kk += 32) {
    f32x4 s0v = (f32x4){0.f, 0.f, 0.f, 0.f};
    f32x4 s1v = (f32x4){0.f, 0.f, 0.f, 0.f};
#pragma unroll
    for (int cc = 0; cc < 4; ++cc) {
      const bf16x8 kb0 =
          *(const bf16x8*)&kp[(size_t)(kk + l16) * HH + cc * 32 + quad * 8];
      const bf16x8 kb1 =
          *(const bf16x8*)&kp[(size_t)(kk + 16 + l16) * HH + cc * 32 + quad * 8];
      s0v = __builtin_amdgcn_mfma_f32_16x16x32_bf16(qf[cc], kb0, s0v, 0, 0, 0);
      s1v = __builtin_amdgcn_mfma_f32_16x16x32_bf16(qf[cc], kb1, s1v, 0, 0, 0);
    }
#pragma unroll
    for (int rr = 0; rr < 4; ++rr) {
      const int rowg = qrb + quad * 4 + rr;
      const float e0 = (kk + l16 <= rowg) ? exp2f(s0v[rr]) : 0.f;
      const float e1 = (kk + 16 + l16 <= rowg) ? exp2f(s1v[rr]) : 0.f;
      P_s[w][(quad * 4 + rr) * 40 + l16] = (__bf16)e0;
      P_s[w][(quad * 4 + rr) * 40 + 16 + l16] = (__bf16)e1;
      lp[rr] += e0 + e1;
    }
    const bf16x8 pa = *(const bf16x8*)&P_s[w][l16 * 40 + quad * 8];
#pragma unroll
    for (int f = 0; f < 8; ++f) {
      const bf16x8 vb =
          *(const bf16x8*)&vt[(size_t)(f * 16 + l16) * SS + kk + quad * 8];
      of[f] = __builtin_amdgcn_mfma_f32_16x16x32_bf16(pa, vb, of[f], 0, 0, 0);
    }
  }

#pragma unroll
  for (int m = 1; m < 16; m <<= 1)
#pragma unroll
    for (int rr = 0; rr < 4; ++rr) lp[rr] += __shfl_xor(lp[rr], m);

  // in-block merge: waves 1..3 publish, wave 0 accumulates
  if (w > 0) {
    float* mb = mbuf + (w - 1) * 2048;
#pragma unroll
    for (int f = 0; f < 8; ++f)
#pragma unroll
      for (int rr = 0; rr < 4; ++rr)
        mb[(quad * 4 + rr) * 128 + f * 16 + l16] = of[f][rr];
    if (l16 == 0)
#pragma unroll
      for (int rr = 0; rr < 4; ++rr) l_buf[w - 1][quad * 4 + rr] = lp[rr];
  }
  __syncthreads();
  if (w == 0) {
    float ls[4];
#pragma unroll
    for (int rr = 0; rr < 4; ++rr)
      ls[rr] = lp[rr] + l_buf[0][quad * 4 + rr] + l_buf[1][quad * 4 + rr] +
               l_buf[2][quad * 4 + rr];
#pragma unroll
    for (int wv = 0; wv < 3; ++wv)
#pragma unroll
      for (int f = 0; f < 8; ++f)
#pragma unroll
        for (int rr = 0; rr < 4; ++rr)
          of[f][rr] += mbuf[wv * 2048 + (quad * 4 + rr) * 128 + f * 16 + l16];

    if (gb == 0) {  // single chunk: finalize directly
#pragma unroll
      for (int rr = 0; rr < 4; ++rr) {
        const float inv = 1.0f / ls[rr];
#pragma unroll
        for (int f = 0; f < 8; ++f)
          out[bq + (size_t)(qrb + quad * 4 + rr) * HH + f * 16 + l16] =
              of[f][rr] * inv;
      }
    } else {
      const int u = b * UNITS_PB + r;
      __bf16* op = Opart + (size_t)u * 2048;
#pragma unroll
      for (int f = 0; f < 8; ++f)
#pragma unroll
        for (int rr = 0; rr < 4; ++rr)
          op[(quad * 4 + rr) * 128 + f * 16 + l16] = (__bf16)of[f][rr];
      if (l16 == 0)
#pragma unroll
        for (int rr = 0; rr < 4; ++rr)
          lpart[u * 16 + quad * 4 + rr] = ls[rr];
    }
  }
}

// ---------------------------------------------------------------------------
// Kernel 3: merge the 2..4 chunk partials for subtiles s>=32. Grid 4*96.
// ---------------------------------------------------------------------------
__global__ __launch_bounds__(256) void attn_merge(
    const __bf16* __restrict__ Opart, const float* __restrict__ lpart,
    float* __restrict__ out) {
  const int b = blockIdx.x / 96;
  const int s = 32 + (blockIdx.x % 96);
  const int gb = s >> 5, nc = gb + 1, sloc = s & 31;
  const int u0 = b * UNITS_PB + 16 * gb * (gb + 1) + sloc * nc;
  const int t = threadIdx.x;
  const int e0 = t * 8, row = e0 >> 7;

  float acc[8] = {0.f, 0.f, 0.f, 0.f, 0.f, 0.f, 0.f, 0.f};
  float lsum = 0.f;
  for (int cc = 0; cc < nc; ++cc) {
    const bf16x8 v = *(const bf16x8*)&Opart[(size_t)(u0 + cc) * 2048 + e0];
#pragma unroll
    for (int i = 0; i < 8; ++i) acc[i] += (float)v[i];
    lsum += lpart[(u0 + cc) * 16 + row];
  }
  const float inv = 1.0f / lsum;
  float4 r0, r1;
  r0.x = acc[0] * inv; r0.y = acc[1] * inv; r0.z = acc[2] * inv; r0.w = acc[3] * inv;
  r1.x = acc[4] * inv; r1.y = acc[5] * inv; r1.z = acc[6] * inv; r1.w = acc[7] * inv;
  float* op = out + (size_t)b * BPLANE + (size_t)s * 2048 + e0;
  ((float4*)op)[0] = r0;
  ((float4*)op)[1] = r1;
}

extern "C" void kernel_launch(void* const* d_in, const int* in_sizes, int n_in,
                              void* d_out, int out_size, void* d_ws, size_t ws_size,
                              hipStream_t stream) {
  const float* x  = (const float*)d_in[0];
  const float* Wq = (const float*)d_in[1];
  const float* Wk = (const float*)d_in[2];
  const float* Wv = (const float*)d_in[3];
  float* out = (float*)d_out;

  // ws: qkv bf16 6.29MB | WT bf16 0.79MB | Opart bf16 5.24MB | lpart 82KB
  char* wsb = (char*)d_ws;
  __bf16* qkv = (__bf16*)wsb;
  __bf16* WT = (__bf16*)(wsb + (size_t)3 * PLANE * 2);
  __bf16* Opart = (__bf16*)(wsb + (size_t)3 * PLANE * 2 + (size_t)3 * HH * EE * 2);
  float* lpart = (float*)(wsb + (size_t)3 * PLANE * 2 + (size_t)3 * HH * EE * 2 +
                          (size_t)BB * UNITS_PB * 2048 * 2);

  prep_w<<<384, 256, 0, stream>>>(Wq, Wk, Wv, WT);
  qkv_proj<<<BB * SS / 32, 256, 0, stream>>>(x, WT, qkv);
  flash_attn_mfma<<<BB * UNITS_PB, 256, 0, stream>>>(qkv, out, Opart, lpart);
  attn_merge<<<BB * 96, 256, 0, stream>>>(Opart, lpart, out);
}

// Round 5
// 181.126 us; speedup vs baseline: 1.0063x; 1.0063x over previous
//
#include <hip/hip_runtime.h>
#include <math.h>

// B,S,E,H = 4,2048,1024,128
#define BB 4
#define SS 2048
#define EE 1024
#define HH 128
#define PLANE (BB * SS * HH)   // per-plane elems
#define BPLANE (SS * HH)       // per-batch elems
#define UNITS_PB 544           // sum over 64 32-row tiles of ceil(32(t+1)/128)

typedef __bf16 bf16x8 __attribute__((ext_vector_type(8)));
typedef __bf16 bf16x4 __attribute__((ext_vector_type(4)));
typedef float f32x4 __attribute__((ext_vector_type(4)));

#define QSCALE (0.08838834764831845f * 1.4426950408889634f)  // 1/sqrt(H)*log2e

// ---------------------------------------------------------------------------
// Kernel 0: W -> WT bf16 transpose. WT[p][n][k]. 384 blocks, 32x32 tiles.
// ---------------------------------------------------------------------------
__global__ __launch_bounds__(256) void prep_w(
    const float* __restrict__ Wq, const float* __restrict__ Wk,
    const float* __restrict__ Wv, __bf16* __restrict__ WT) {
  __shared__ float LT[32 * 33];
  const int p = blockIdx.x >> 7;
  const int r = blockIdx.x & 127;
  const int kb = (r >> 2) * 32, nb = (r & 3) * 32;
  const float* __restrict__ W = (p == 0) ? Wq : (p == 1) ? Wk : Wv;
  const int t = threadIdx.x;
  const int kr = t >> 3, nc4 = (t & 7) * 4;
  const float4 v = *(const float4*)&W[(size_t)(kb + kr) * HH + nb + nc4];
  LT[(nc4 + 0) * 33 + kr] = v.x;
  LT[(nc4 + 1) * 33 + kr] = v.y;
  LT[(nc4 + 2) * 33 + kr] = v.z;
  LT[(nc4 + 3) * 33 + kr] = v.w;
  __syncthreads();
  const int n = t >> 3, kc = (t & 7) * 4;
  bf16x4 o;
#pragma unroll
  for (int i = 0; i < 4; ++i) o[i] = (__bf16)LT[n * 33 + kc + i];
  *(bf16x4*)&WT[(size_t)p * (HH * EE) + (size_t)(nb + n) * EE + kb + kc] = o;
}

// ---------------------------------------------------------------------------
// Kernel 1: QKV projection — NO LDS, NO barriers. Grid (256, 2), block = 4
// waves. Wave = 16 rows x 96 cols. A-frags: fp32 x loads (16 rows x 128 B
// contiguous per instr) packed to bf16 in-register; B-frags: direct bf16x8
// from L2-hot WT. 12 MFMA per wave-step, 16 steps (BK=64).
// q scaled by QSCALE; v written transposed vT[b][d][s].
// ---------------------------------------------------------------------------
__global__ __launch_bounds__(256) void qkv_proj(
    const float* __restrict__ x, const __bf16* __restrict__ WT,
    __bf16* __restrict__ qkv) {
  const int t = threadIdx.x, w = t >> 6, lane = t & 63;
  const int quad = lane >> 4, l16 = lane & 15;
  const int rowbase = blockIdx.x * 32 + (w >> 1) * 16;
  const int colbase = blockIdx.y * 192 + (w & 1) * 96;

  f32x4 acc[6];
#pragma unroll
  for (int j = 0; j < 6; ++j) acc[j] = (f32x4){0.f, 0.f, 0.f, 0.f};

  const float* __restrict__ xr = x + (size_t)(rowbase + l16) * EE;

#pragma unroll 2
  for (int kt = 0; kt < 16; ++kt) {
    bf16x8 af[2];
#pragma unroll
    for (int cc = 0; cc < 2; ++cc) {
      const float4 u0 = *(const float4*)&xr[kt * 64 + cc * 32 + quad * 8];
      const float4 u1 = *(const float4*)&xr[kt * 64 + cc * 32 + quad * 8 + 4];
      af[cc][0] = (__bf16)u0.x; af[cc][1] = (__bf16)u0.y;
      af[cc][2] = (__bf16)u0.z; af[cc][3] = (__bf16)u0.w;
      af[cc][4] = (__bf16)u1.x; af[cc][5] = (__bf16)u1.y;
      af[cc][6] = (__bf16)u1.z; af[cc][7] = (__bf16)u1.w;
    }
#pragma unroll
    for (int j = 0; j < 6; ++j) {
      const int c0 = colbase + j * 16;
      const int p = c0 >> 7, n0 = c0 & 127;
      const __bf16* bp = WT + (size_t)p * (HH * EE) +
                         (size_t)(n0 + l16) * EE + kt * 64 + quad * 8;
#pragma unroll
      for (int cc = 0; cc < 2; ++cc) {
        const bf16x8 bfr = *(const bf16x8*)(bp + cc * 32);
        acc[j] = __builtin_amdgcn_mfma_f32_16x16x32_bf16(af[cc], bfr, acc[j], 0, 0, 0);
      }
    }
  }

#pragma unroll
  for (int j = 0; j < 6; ++j) {
    const int c0 = colbase + j * 16;
    const int p = c0 >> 7, n0 = c0 & 127;
    const int srow0 = rowbase + quad * 4;
    if (p < 2) {
      const float scale = (p == 0) ? QSCALE : 1.0f;
      __bf16* outp = qkv + (size_t)p * PLANE;
#pragma unroll
      for (int rr = 0; rr < 4; ++rr)
        outp[(size_t)(srow0 + rr) * HH + n0 + l16] = (__bf16)(acc[j][rr] * scale);
    } else {
      const int b = srow0 >> 11, sl = srow0 & 2047;
      const int d = n0 + l16;
      bf16x4 vv;
#pragma unroll
      for (int rr = 0; rr < 4; ++rr) vv[rr] = (__bf16)acc[j][rr];
      *(bf16x4*)&qkv[2 * (size_t)PLANE + (size_t)b * BPLANE + (size_t)d * SS + sl] = vv;
    }
  }
}

// ---------------------------------------------------------------------------
// Kernel 2: causal attention — ZERO LDS, zero barriers, wave-independent.
// Wave-unit = (batch b = wave id, 32 q-rows, 128-k chunk). Compute S^T via
// swapped MFMA operands (A = K rows with permuted row map (m>>2)*8+(m&3) and
// +4), so the C-layout of S^T IS the A-fragment of P for the PV 16x16x32 MFMA
// — exp2 + pack entirely in registers. 2 q-subtiles share all K/V fragments.
// Block = same (tile,chunk) for 4 batches => uniform block duration.
// nc==1 units (t0<4) normalize + write fp32 out; others write bf16 partials.
// ---------------------------------------------------------------------------
__global__ __launch_bounds__(256, 2) void flash_attn_mfma(
    const __bf16* __restrict__ qkv, float* __restrict__ out,
    __bf16* __restrict__ Opart, float* __restrict__ lpart) {
  const int t = threadIdx.x, w = t >> 6, lane = t & 63;
  const int quad = lane >> 4, l16 = lane & 15;
  const int b = w;                                 // wave = batch
  const int r = (UNITS_PB - 1) - blockIdx.x;       // heavy-first
  int g = 0;
  while (2 * (g + 1) * (g + 2) <= r) ++g;          // g = t0>>2, nc = g+1
  const int rem = r - 2 * g * (g + 1);
  const int nc = g + 1;
  const int v = rem / nc, c = rem % nc;
  const int t0 = 4 * g + v;                        // 32-row q-tile, 0..63
  const int qrb = t0 * 32;
  const int k0 = c * 128;
  const int kend = min(k0 + 128, qrb + 32);

  const size_t bq = (size_t)b * BPLANE;
  const __bf16* __restrict__ qp = qkv + bq;
  const __bf16* __restrict__ kp = qkv + PLANE + bq;
  const __bf16* __restrict__ vt = qkv + 2 * (size_t)PLANE + bq;  // [d][s]

  bf16x8 qf[2][4];
#pragma unroll
  for (int sub = 0; sub < 2; ++sub)
#pragma unroll
    for (int cc = 0; cc < 4; ++cc)
      qf[sub][cc] = *(const bf16x8*)&qp[(size_t)(qrb + sub * 16 + l16) * HH +
                                        cc * 32 + quad * 8];

  f32x4 of[2][8];
#pragma unroll
  for (int sub = 0; sub < 2; ++sub)
#pragma unroll
    for (int f = 0; f < 8; ++f) of[sub][f] = (f32x4){0.f, 0.f, 0.f, 0.f};
  float lp[2] = {0.f, 0.f};

  const int pu = (l16 >> 2) * 8 + (l16 & 3);  // permuted K-row (U set)

  for (int kk = k0; kk < kend; kk += 32) {
    // K A-fragments, permuted rows: U covers k=quad*8+rr, V covers +4
    bf16x8 ku[4], kv[4];
#pragma unroll
    for (int cc = 0; cc < 4; ++cc) {
      ku[cc] = *(const bf16x8*)&kp[(size_t)(kk + pu) * HH + cc * 32 + quad * 8];
      kv[cc] = *(const bf16x8*)&kp[(size_t)(kk + pu + 4) * HH + cc * 32 + quad * 8];
    }
    f32x4 su[2] = {(f32x4){0.f, 0.f, 0.f, 0.f}, (f32x4){0.f, 0.f, 0.f, 0.f}};
    f32x4 sv[2] = {(f32x4){0.f, 0.f, 0.f, 0.f}, (f32x4){0.f, 0.f, 0.f, 0.f}};
#pragma unroll
    for (int cc = 0; cc < 4; ++cc)
#pragma unroll
      for (int sub = 0; sub < 2; ++sub) {
        su[sub] = __builtin_amdgcn_mfma_f32_16x16x32_bf16(ku[cc], qf[sub][cc], su[sub], 0, 0, 0);
        sv[sub] = __builtin_amdgcn_mfma_f32_16x16x32_bf16(kv[cc], qf[sub][cc], sv[sub], 0, 0, 0);
      }
    // lane holds S^T: q = l16, k = kk + quad*8 + rr (U) / +4 (V)
    bf16x8 pa[2];
#pragma unroll
    for (int sub = 0; sub < 2; ++sub) {
      const int qg = qrb + sub * 16 + l16;
#pragma unroll
      for (int rr = 0; rr < 4; ++rr) {
        const int kU = kk + quad * 8 + rr;
        const float eU = (kU <= qg) ? exp2f(su[sub][rr]) : 0.f;
        const float eV = (kU + 4 <= qg) ? exp2f(sv[sub][rr]) : 0.f;
        pa[sub][rr] = (__bf16)eU;
        pa[sub][4 + rr] = (__bf16)eV;
        lp[sub] += eU + eV;
      }
    }
    // PV: pa is exactly the A-fragment; V B-frags from vT (shared by subs)
#pragma unroll
    for (int f = 0; f < 8; ++f) {
      const bf16x8 vb =
          *(const bf16x8*)&vt[(size_t)(f * 16 + l16) * SS + kk + quad * 8];
#pragma unroll
      for (int sub = 0; sub < 2; ++sub)
        of[sub][f] = __builtin_amdgcn_mfma_f32_16x16x32_bf16(pa[sub], vb, of[sub][f], 0, 0, 0);
    }
  }

  // l: every lane has partial for q=l16; reduce across the 4 quads
#pragma unroll
  for (int sub = 0; sub < 2; ++sub) {
    lp[sub] += __shfl_xor(lp[sub], 16);
    lp[sub] += __shfl_xor(lp[sub], 32);
  }

  if (nc == 1) {  // single chunk: finalize (O rows are q=quad*4+rr)
#pragma unroll
    for (int sub = 0; sub < 2; ++sub)
#pragma unroll
      for (int rr = 0; rr < 4; ++rr) {
        const float lrow = __shfl(lp[sub], quad * 4 + rr);
        const float inv = 1.0f / lrow;
#pragma unroll
        for (int f = 0; f < 8; ++f)
          out[bq + (size_t)(qrb + sub * 16 + quad * 4 + rr) * HH + f * 16 + l16] =
              of[sub][f][rr] * inv;
      }
  } else {
    const int u = b * UNITS_PB + r;
    __bf16* op = Opart + (size_t)u * 4096;
#pragma unroll
    for (int sub = 0; sub < 2; ++sub)
#pragma unroll
      for (int f = 0; f < 8; ++f)
#pragma unroll
        for (int rr = 0; rr < 4; ++rr)
          op[(sub * 16 + quad * 4 + rr) * 128 + f * 16 + l16] = (__bf16)of[sub][f][rr];
    if (quad == 0) {
      lpart[u * 32 + l16] = lp[0];
      lpart[u * 32 + 16 + l16] = lp[1];
    }
  }
}

// ---------------------------------------------------------------------------
// Kernel 3: merge chunk partials for tiles t0 >= 4. Grid 4*60 blocks.
// ---------------------------------------------------------------------------
__global__ __launch_bounds__(256) void attn_merge(
    const __bf16* __restrict__ Opart, const float* __restrict__ lpart,
    float* __restrict__ out) {
  const int b = blockIdx.x / 60;
  const int t0 = 4 + (blockIdx.x % 60);
  const int g = t0 >> 2, v = t0 & 3, nc = g + 1;
  const int u0 = b * UNITS_PB + 2 * g * (g + 1) + v * nc;
  const int t = threadIdx.x;
#pragma unroll
  for (int i = 0; i < 2; ++i) {
    const int e0 = i * 2048 + t * 8;
    const int row = e0 >> 7;
    float acc[8] = {0.f, 0.f, 0.f, 0.f, 0.f, 0.f, 0.f, 0.f};
    float lsum = 0.f;
    for (int cc = 0; cc < nc; ++cc) {
      const bf16x8 pv = *(const bf16x8*)&Opart[(size_t)(u0 + cc) * 4096 + e0];
#pragma unroll
      for (int k = 0; k < 8; ++k) acc[k] += (float)pv[k];
      lsum += lpart[(u0 + cc) * 32 + row];
    }
    const float inv = 1.0f / lsum;
    float4 r0, r1;
    r0.x = acc[0] * inv; r0.y = acc[1] * inv; r0.z = acc[2] * inv; r0.w = acc[3] * inv;
    r1.x = acc[4] * inv; r1.y = acc[5] * inv; r1.z = acc[6] * inv; r1.w = acc[7] * inv;
    float* op = out + (size_t)b * BPLANE + (size_t)t0 * 4096 + e0;
    ((float4*)op)[0] = r0;
    ((float4*)op)[1] = r1;
  }
}

extern "C" void kernel_launch(void* const* d_in, const int* in_sizes, int n_in,
                              void* d_out, int out_size, void* d_ws, size_t ws_size,
                              hipStream_t stream) {
  const float* x  = (const float*)d_in[0];
  const float* Wq = (const float*)d_in[1];
  const float* Wk = (const float*)d_in[2];
  const float* Wv = (const float*)d_in[3];
  float* out = (float*)d_out;

  // ws: qkv bf16 6.29MB | WT bf16 0.79MB | Opart bf16 17.8MB | lpart 0.28MB
  char* wsb = (char*)d_ws;
  __bf16* qkv = (__bf16*)wsb;
  __bf16* WT = (__bf16*)(wsb + (size_t)3 * PLANE * 2);
  __bf16* Opart = (__bf16*)(wsb + (size_t)3 * PLANE * 2 + (size_t)3 * HH * EE * 2);
  float* lpart = (float*)(wsb + (size_t)3 * PLANE * 2 + (size_t)3 * HH * EE * 2 +
                          (size_t)BB * UNITS_PB * 4096 * 2);

  prep_w<<<384, 256, 0, stream>>>(Wq, Wk, Wv, WT);
  qkv_proj<<<dim3(BB * SS / 32, 2), 256, 0, stream>>>(x, WT, qkv);
  flash_attn_mfma<<<UNITS_PB, 256, 0, stream>>>(qkv, out, Opart, lpart);
  attn_merge<<<BB * 60, 256, 0, stream>>>(Opart, lpart, out);
}

// Round 6
// 129.594 us; speedup vs baseline: 1.4064x; 1.3976x over previous
//
#include <hip/hip_runtime.h>
#include <math.h>

// B,S,E,H = 4,2048,1024,128
#define BB 4
#define SS 2048
#define EE 1024
#define HH 128
#define PLANE (BB * SS * HH)
#define BPLANE (SS * HH)
#define AUNITS 144  // per batch: sum over 32 64-row tiles of ceil(64(t+1)/256)

typedef __bf16 bf16x8 __attribute__((ext_vector_type(8)));
typedef __bf16 bf16x4 __attribute__((ext_vector_type(4)));
typedef float f32x4 __attribute__((ext_vector_type(4)));

#define QSCALE (0.08838834764831845f * 1.4426950408889634f)  // 1/sqrt(H)*log2e

// ---------------------------------------------------------------------------
// Kernel 0: W -> WT bf16 transpose. WT[p][n][k]. 384 blocks, 32x32 tiles.
// ---------------------------------------------------------------------------
__global__ __launch_bounds__(256) void prep_w(
    const float* __restrict__ Wq, const float* __restrict__ Wk,
    const float* __restrict__ Wv, __bf16* __restrict__ WT) {
  __shared__ float LT[32 * 33];
  const int p = blockIdx.x >> 7;
  const int r = blockIdx.x & 127;
  const int kb = (r >> 2) * 32, nb = (r & 3) * 32;
  const float* __restrict__ W = (p == 0) ? Wq : (p == 1) ? Wk : Wv;
  const int t = threadIdx.x;
  const int kr = t >> 3, nc4 = (t & 7) * 4;
  const float4 v = *(const float4*)&W[(size_t)(kb + kr) * HH + nb + nc4];
  LT[(nc4 + 0) * 33 + kr] = v.x;
  LT[(nc4 + 1) * 33 + kr] = v.y;
  LT[(nc4 + 2) * 33 + kr] = v.z;
  LT[(nc4 + 3) * 33 + kr] = v.w;
  __syncthreads();
  const int n = t >> 3, kc = (t & 7) * 4;
  bf16x4 o;
#pragma unroll
  for (int i = 0; i < 4; ++i) o[i] = (__bf16)LT[n * 33 + kc + i];
  *(bf16x4*)&WT[(size_t)p * (HH * EE) + (size_t)(nb + n) * EE + kb + kc] = o;
}

// ---------------------------------------------------------------------------
// Kernel 1: QKV projection. Grid (64,3), block 512 = 8 waves.
// BM=128, BN=128; waves split K: kg0 -> k[0,512), kg1 -> k[512,1024), each kg
// a 2x2 wave grid of 64x64 tiles, BK=32 double-buffered with reg prefetch.
// x staged fp32->bf16 (stride 40), WT staged bf16 (stride 40). 16 MFMA per
// wave-step. kg1 publishes acc via LDS; kg0 merges + writes bf16 q/k/vT.
// ---------------------------------------------------------------------------
__global__ __launch_bounds__(512, 2) void qkv_proj(
    const float* __restrict__ x, const __bf16* __restrict__ WT,
    __bf16* __restrict__ qkv) {
  __shared__ __align__(16) char smem[81920];
  __bf16* xs = (__bf16*)smem;              // [kg*2+buf][128*40]
  __bf16* wsd = (__bf16*)(smem + 40960);   // [kg*2+buf][128*40]

  const int t = threadIdx.x, w = t >> 6, lane = t & 63;
  const int quad = lane >> 4, l16 = lane & 15;
  const int kg = w >> 2, wl = w & 3;
  const int t2 = t & 255;
  const int mb = blockIdx.x * 128;
  const int proj = blockIdx.y;
  const __bf16* __restrict__ WTp = WT + (size_t)proj * (HH * EE);
  const int wm = (wl >> 1) * 64, wn = (wl & 1) * 64;
  const int kb0 = kg * 512;

  f32x4 acc[4][4];
#pragma unroll
  for (int i = 0; i < 4; ++i)
#pragma unroll
    for (int j = 0; j < 4; ++j) acc[i][j] = (f32x4){0.f, 0.f, 0.f, 0.f};

  // prologue: stage k-tile 0 of this kg into buf 0
  {
    __bf16* xb = xs + (size_t)(kg * 2) * 5120;
    __bf16* wb = wsd + (size_t)(kg * 2) * 5120;
#pragma unroll
    for (int i = 0; i < 4; ++i) {
      const int idx = t2 + i * 256;
      const int row = idx >> 3, kc = (idx & 7) * 4;
      const float4 v = *(const float4*)&x[(size_t)(mb + row) * EE + kb0 + kc];
      bf16x4 bv;
      bv[0] = (__bf16)v.x; bv[1] = (__bf16)v.y;
      bv[2] = (__bf16)v.z; bv[3] = (__bf16)v.w;
      *(bf16x4*)&xb[row * 40 + kc] = bv;
    }
#pragma unroll
    for (int i = 0; i < 2; ++i) {
      const int idx = t2 + i * 256;
      const int n = idx >> 2, kc8 = (idx & 3) * 8;
      *(bf16x8*)&wb[n * 40 + kc8] =
          *(const bf16x8*)&WTp[(size_t)n * EE + kb0 + kc8];
    }
  }
  __syncthreads();

  for (int kt = 0; kt < 16; ++kt) {
    const int cur = kt & 1;
    float4 xr[4];
    bf16x8 wr[2];
    if (kt < 15) {
      const int kb = kb0 + (kt + 1) * 32;
#pragma unroll
      for (int i = 0; i < 4; ++i) {
        const int idx = t2 + i * 256;
        const int row = idx >> 3, kc = (idx & 7) * 4;
        xr[i] = *(const float4*)&x[(size_t)(mb + row) * EE + kb + kc];
      }
#pragma unroll
      for (int i = 0; i < 2; ++i) {
        const int idx = t2 + i * 256;
        const int n = idx >> 2, kc8 = (idx & 3) * 8;
        wr[i] = *(const bf16x8*)&WTp[(size_t)n * EE + kb + kc8];
      }
    }

    const __bf16* xb = xs + (size_t)(kg * 2 + cur) * 5120;
    const __bf16* wb = wsd + (size_t)(kg * 2 + cur) * 5120;
    bf16x8 af[4], bfr[4];
#pragma unroll
    for (int i = 0; i < 4; ++i)
      af[i] = *(const bf16x8*)&xb[(wm + i * 16 + l16) * 40 + quad * 8];
#pragma unroll
    for (int j = 0; j < 4; ++j)
      bfr[j] = *(const bf16x8*)&wb[(wn + j * 16 + l16) * 40 + quad * 8];
#pragma unroll
    for (int i = 0; i < 4; ++i)
#pragma unroll
      for (int j = 0; j < 4; ++j)
        acc[i][j] = __builtin_amdgcn_mfma_f32_16x16x32_bf16(
            af[i], bfr[j], acc[i][j], 0, 0, 0);

    if (kt < 15) {
      __bf16* xb1 = xs + (size_t)(kg * 2 + (cur ^ 1)) * 5120;
      __bf16* wb1 = wsd + (size_t)(kg * 2 + (cur ^ 1)) * 5120;
#pragma unroll
      for (int i = 0; i < 4; ++i) {
        const int idx = t2 + i * 256;
        const int row = idx >> 3, kc = (idx & 7) * 4;
        bf16x4 bv;
        bv[0] = (__bf16)xr[i].x; bv[1] = (__bf16)xr[i].y;
        bv[2] = (__bf16)xr[i].z; bv[3] = (__bf16)xr[i].w;
        *(bf16x4*)&xb1[row * 40 + kc] = bv;
      }
#pragma unroll
      for (int i = 0; i < 2; ++i) {
        const int idx = t2 + i * 256;
        const int n = idx >> 2, kc8 = (idx & 3) * 8;
        *(bf16x8*)&wb1[n * 40 + kc8] = wr[i];
      }
    }
    __syncthreads();
  }

  // split-K merge: kg1 publishes, kg0 accumulates + stores
  float* mbuf = (float*)smem;  // 4 waves x 16 KB = 64 KB (fits in 80 KB)
  if (kg == 1) {
    float* mb = mbuf + (size_t)wl * 4096;
#pragma unroll
    for (int i = 0; i < 4; ++i)
#pragma unroll
      for (int j = 0; j < 4; ++j)
#pragma unroll
        for (int rr = 0; rr < 4; ++rr)
          mb[(i * 16 + quad * 4 + rr) * 64 + j * 16 + l16] = acc[i][j][rr];
  }
  __syncthreads();
  if (kg == 0) {
    const float* mb = mbuf + (size_t)wl * 4096;
#pragma unroll
    for (int i = 0; i < 4; ++i)
#pragma unroll
      for (int j = 0; j < 4; ++j)
#pragma unroll
        for (int rr = 0; rr < 4; ++rr)
          acc[i][j][rr] += mb[(i * 16 + quad * 4 + rr) * 64 + j * 16 + l16];

    if (proj < 2) {
      const float scale = (proj == 0) ? QSCALE : 1.0f;
      __bf16* outp = qkv + (size_t)proj * PLANE;
#pragma unroll
      for (int i = 0; i < 4; ++i) {
        const int s0 = mb == 0 ? 0 : 0;  // (dummy to keep compiler quiet)
        const int srow = (blockIdx.x * 128) + wm + i * 16 + quad * 4;
#pragma unroll
        for (int j = 0; j < 4; ++j)
#pragma unroll
          for (int rr = 0; rr < 4; ++rr)
            outp[(size_t)(srow + rr) * HH + wn + j * 16 + l16] =
                (__bf16)(acc[i][j][rr] * scale);
      }
    } else {
      __bf16* vtp = qkv + 2 * (size_t)PLANE;
#pragma unroll
      for (int i = 0; i < 4; ++i) {
        const int srow = (blockIdx.x * 128) + wm + i * 16 + quad * 4;
        const int bb = srow >> 11, sl = srow & 2047;
#pragma unroll
        for (int j = 0; j < 4; ++j) {
          const int d = wn + j * 16 + l16;
          bf16x4 vv;
#pragma unroll
          for (int rr = 0; rr < 4; ++rr) vv[rr] = (__bf16)acc[i][j][rr];
          *(bf16x4*)&vtp[(size_t)bb * BPLANE + (size_t)d * SS + sl] = vv;
        }
      }
    }
  }
}

// ---------------------------------------------------------------------------
// Kernel 2: causal attention. Block = (b, 64 q-rows, 256-k chunk), 576 blocks
// (2/CU by LDS). K and VT staged coalesced into double-buffered LDS with
// register prefetch, 1 barrier/64k-tile. K rows stored lambda-permuted so the
// S^T trick (C-layout == PV A-fragment) uses standard column ds_reads.
// Wave = 16 q-rows. nc==1 units write fp32 out; else bf16 partials + l.
// ---------------------------------------------------------------------------
__global__ __launch_bounds__(256, 2) void flash_attn_mfma(
    const __bf16* __restrict__ qkv, float* __restrict__ out,
    __bf16* __restrict__ Opart, float* __restrict__ lpart) {
  __shared__ __align__(16) __bf16 K_s[2][64 * 136];
  __shared__ __align__(16) __bf16 VT_s[2][128 * 72];

  const int t = threadIdx.x, w = t >> 6, lane = t & 63;
  const int quad = lane >> 4, l16 = lane & 15;
  const int b = blockIdx.x & 3;
  const int r = (AUNITS - 1) - (blockIdx.x >> 2);  // heavy-first
  int g = 0;
  while (2 * (g + 1) * (g + 2) <= r) ++g;  // g = tile>>2, nc = g+1
  const int rem = r - 2 * g * (g + 1);
  const int nc = g + 1;
  const int tloc = rem / nc, c = rem % nc;
  const int tile = 4 * g + tloc;
  const int qrb = tile * 64;
  const int k0 = c * 256;
  const int kend = min(k0 + 256, qrb + 64);
  const int ntiles = (kend - k0) >> 6;  // 1..4 (always multiples of 64)
  const int qsb = qrb + w * 16;

  const size_t bq = (size_t)b * BPLANE;
  const __bf16* __restrict__ qp = qkv + bq;
  const __bf16* __restrict__ kp = qkv + PLANE + bq;
  const __bf16* __restrict__ vt = qkv + 2 * (size_t)PLANE + bq;  // [d][s]

  bf16x8 qf[4];
#pragma unroll
  for (int cc = 0; cc < 4; ++cc)
    qf[cc] = *(const bf16x8*)&qp[(size_t)(qsb + l16) * HH + cc * 32 + quad * 8];

  f32x4 of[8];
#pragma unroll
  for (int f = 0; f < 8; ++f) of[f] = (f32x4){0.f, 0.f, 0.f, 0.f};
  float lp = 0.f;  // per lane: q = qsb + l16

  // prologue: stage tile 0 into buf 0
  {
#pragma unroll
    for (int i = 0; i < 4; ++i) {
      const int idx = t + i * 256;
      const int row = idx >> 4, dc = (idx & 15) * 8;
      const int lam = (row & 32) + ((row & 4) ? 16 : 0) +
                      (((row & 31) >> 3) << 2) + (row & 3);
      *(bf16x8*)&K_s[0][lam * 136 + dc] =
          *(const bf16x8*)&kp[(size_t)(k0 + row) * HH + dc];
    }
#pragma unroll
    for (int i = 0; i < 4; ++i) {
      const int idx = t + i * 256;
      const int d = idx >> 3, kc = (idx & 7) * 8;
      *(bf16x8*)&VT_s[0][d * 72 + kc] =
          *(const bf16x8*)&vt[(size_t)d * SS + k0 + kc];
    }
  }
  __syncthreads();

  for (int jt = 0; jt < ntiles; ++jt) {
    const int cur = jt & 1;
    bf16x8 krg[4], vrg[4];
    if (jt + 1 < ntiles) {
      const int kb2 = k0 + (jt + 1) * 64;
#pragma unroll
      for (int i = 0; i < 4; ++i) {
        const int idx = t + i * 256;
        const int row = idx >> 4, dc = (idx & 15) * 8;
        krg[i] = *(const bf16x8*)&kp[(size_t)(kb2 + row) * HH + dc];
      }
#pragma unroll
      for (int i = 0; i < 4; ++i) {
        const int idx = t + i * 256;
        const int d = idx >> 3, kc = (idx & 7) * 8;
        vrg[i] = *(const bf16x8*)&vt[(size_t)d * SS + kb2 + kc];
      }
    }

    const __bf16* Kc = K_s[cur];
    const __bf16* Vc = VT_s[cur];
#pragma unroll
    for (int s32 = 0; s32 < 2; ++s32) {
      const int kabs = k0 + jt * 64 + s32 * 32;
      if (kabs <= qsb + 15) {  // wave-uniform: skip fully-masked steps
        bf16x8 ku[4], kv[4];
#pragma unroll
        for (int cc = 0; cc < 4; ++cc) {
          ku[cc] = *(const bf16x8*)&Kc[(s32 * 32 + l16) * 136 + cc * 32 + quad * 8];
          kv[cc] = *(const bf16x8*)&Kc[(s32 * 32 + 16 + l16) * 136 + cc * 32 + quad * 8];
        }
        f32x4 su = (f32x4){0.f, 0.f, 0.f, 0.f};
        f32x4 sv = (f32x4){0.f, 0.f, 0.f, 0.f};
#pragma unroll
        for (int cc = 0; cc < 4; ++cc) {
          su = __builtin_amdgcn_mfma_f32_16x16x32_bf16(ku[cc], qf[cc], su, 0, 0, 0);
          sv = __builtin_amdgcn_mfma_f32_16x16x32_bf16(kv[cc], qf[cc], sv, 0, 0, 0);
        }
        const int qg = qsb + l16;
        bf16x8 pa;
#pragma unroll
        for (int rr = 0; rr < 4; ++rr) {
          const int kU = kabs + quad * 8 + rr;
          const float eU = (kU <= qg) ? exp2f(su[rr]) : 0.f;
          const float eV = (kU + 4 <= qg) ? exp2f(sv[rr]) : 0.f;
          pa[rr] = (__bf16)eU;
          pa[4 + rr] = (__bf16)eV;
          lp += eU + eV;
        }
#pragma unroll
        for (int f = 0; f < 8; ++f) {
          const bf16x8 vb =
              *(const bf16x8*)&Vc[(f * 16 + l16) * 72 + s32 * 32 + quad * 8];
          of[f] = __builtin_amdgcn_mfma_f32_16x16x32_bf16(pa, vb, of[f], 0, 0, 0);
        }
      }
    }

    if (jt + 1 < ntiles) {
      const int nxt = cur ^ 1;
#pragma unroll
      for (int i = 0; i < 4; ++i) {
        const int idx = t + i * 256;
        const int row = idx >> 4, dc = (idx & 15) * 8;
        const int lam = (row & 32) + ((row & 4) ? 16 : 0) +
                        (((row & 31) >> 3) << 2) + (row & 3);
        *(bf16x8*)&K_s[nxt][lam * 136 + dc] = krg[i];
      }
#pragma unroll
      for (int i = 0; i < 4; ++i) {
        const int idx = t + i * 256;
        const int d = idx >> 3, kc = (idx & 7) * 8;
        *(bf16x8*)&VT_s[nxt][d * 72 + kc] = vrg[i];
      }
    }
    __syncthreads();
  }

  // reduce l across quads (lane q = l16)
  lp += __shfl_xor(lp, 16);
  lp += __shfl_xor(lp, 32);

  if (nc == 1) {  // single chunk: finalize (O rows q = quad*4+rr)
#pragma unroll
    for (int rr = 0; rr < 4; ++rr) {
      const float lrow = __shfl(lp, quad * 4 + rr);
      const float inv = 1.0f / lrow;
#pragma unroll
      for (int f = 0; f < 8; ++f)
        out[bq + (size_t)(qsb + quad * 4 + rr) * HH + f * 16 + l16] =
            of[f][rr] * inv;
    }
  } else {
    const int u = b * AUNITS + r;
    __bf16* op = Opart + (size_t)u * 8192;
#pragma unroll
    for (int f = 0; f < 8; ++f)
#pragma unroll
      for (int rr = 0; rr < 4; ++rr)
        op[(w * 16 + quad * 4 + rr) * 128 + f * 16 + l16] = (__bf16)of[f][rr];
    if (quad == 0) lpart[u * 64 + w * 16 + l16] = lp;
  }
}

// ---------------------------------------------------------------------------
// Kernel 3: merge chunk partials for 64-row tiles >= 4. Grid 4*28 blocks.
// ---------------------------------------------------------------------------
__global__ __launch_bounds__(256) void attn_merge(
    const __bf16* __restrict__ Opart, const float* __restrict__ lpart,
    float* __restrict__ out) {
  const int b = blockIdx.x / 28;
  const int tile = 4 + (blockIdx.x % 28);
  const int g = tile >> 2, nc = g + 1, tloc = tile - 4 * g;
  const int u0 = b * AUNITS + 2 * g * (g + 1) + tloc * nc;
  const int t = threadIdx.x;
#pragma unroll
  for (int i = 0; i < 4; ++i) {
    const int idx = t + i * 256;
    const int e0 = idx * 8;
    const int row = e0 >> 7;
    float acc[8] = {0.f, 0.f, 0.f, 0.f, 0.f, 0.f, 0.f, 0.f};
    float lsum = 0.f;
    for (int cc = 0; cc < nc; ++cc) {
      const bf16x8 pv = *(const bf16x8*)&Opart[(size_t)(u0 + cc) * 8192 + e0];
#pragma unroll
      for (int k = 0; k < 8; ++k) acc[k] += (float)pv[k];
      lsum += lpart[(u0 + cc) * 64 + row];
    }
    const float inv = 1.0f / lsum;
    float4 r0, r1;
    r0.x = acc[0] * inv; r0.y = acc[1] * inv; r0.z = acc[2] * inv; r0.w = acc[3] * inv;
    r1.x = acc[4] * inv; r1.y = acc[5] * inv; r1.z = acc[6] * inv; r1.w = acc[7] * inv;
    float* op = out + (size_t)b * BPLANE + (size_t)tile * 8192 + e0;
    ((float4*)op)[0] = r0;
    ((float4*)op)[1] = r1;
  }
}

extern "C" void kernel_launch(void* const* d_in, const int* in_sizes, int n_in,
                              void* d_out, int out_size, void* d_ws, size_t ws_size,
                              hipStream_t stream) {
  const float* x  = (const float*)d_in[0];
  const float* Wq = (const float*)d_in[1];
  const float* Wk = (const float*)d_in[2];
  const float* Wv = (const float*)d_in[3];
  float* out = (float*)d_out;

  // ws: qkv bf16 6.29MB | WT bf16 0.79MB | Opart bf16 9.44MB | lpart 0.15MB
  char* wsb = (char*)d_ws;
  __bf16* qkv = (__bf16*)wsb;
  __bf16* WT = (__bf16*)(wsb + (size_t)3 * PLANE * 2);
  __bf16* Opart = (__bf16*)(wsb + (size_t)3 * PLANE * 2 + (size_t)3 * HH * EE * 2);
  float* lpart = (float*)(wsb + (size_t)3 * PLANE * 2 + (size_t)3 * HH * EE * 2 +
                          (size_t)BB * AUNITS * 8192 * 2);

  prep_w<<<384, 256, 0, stream>>>(Wq, Wk, Wv, WT);
  qkv_proj<<<dim3(64, 3), 512, 0, stream>>>(x, WT, qkv);
  flash_attn_mfma<<<BB * AUNITS, 256, 0, stream>>>(qkv, out, Opart, lpart);
  attn_merge<<<BB * 28, 256, 0, stream>>>(Opart, lpart, out);
}

// Round 7
// 129.027 us; speedup vs baseline: 1.4126x; 1.0044x over previous
//
#include <hip/hip_runtime.h>
#include <math.h>

// B,S,E,H = 4,2048,1024,128
#define BB 4
#define SS 2048
#define EE 1024
#define HH 128
#define PLANE (BB * SS * HH)
#define BPLANE (SS * HH)
#define AUNITS 272  // per batch: sum over 32 64-row tiles of ceil(64(t+1)/128)

typedef __bf16 bf16x8 __attribute__((ext_vector_type(8)));
typedef __bf16 bf16x4 __attribute__((ext_vector_type(4)));
typedef float f32x4 __attribute__((ext_vector_type(4)));

#define QSCALE (0.08838834764831845f * 1.4426950408889634f)  // 1/sqrt(H)*log2e

// ---------------------------------------------------------------------------
// Kernel 0: W -> WT bf16 transpose. WT[p][n][k]. 384 blocks, 32x32 tiles.
// ---------------------------------------------------------------------------
__global__ __launch_bounds__(256) void prep_w(
    const float* __restrict__ Wq, const float* __restrict__ Wk,
    const float* __restrict__ Wv, __bf16* __restrict__ WT) {
  __shared__ float LT[32 * 33];
  const int p = blockIdx.x >> 7;
  const int r = blockIdx.x & 127;
  const int kb = (r >> 2) * 32, nb = (r & 3) * 32;
  const float* __restrict__ W = (p == 0) ? Wq : (p == 1) ? Wk : Wv;
  const int t = threadIdx.x;
  const int kr = t >> 3, nc4 = (t & 7) * 4;
  const float4 v = *(const float4*)&W[(size_t)(kb + kr) * HH + nb + nc4];
  LT[(nc4 + 0) * 33 + kr] = v.x;
  LT[(nc4 + 1) * 33 + kr] = v.y;
  LT[(nc4 + 2) * 33 + kr] = v.z;
  LT[(nc4 + 3) * 33 + kr] = v.w;
  __syncthreads();
  const int n = t >> 3, kc = (t & 7) * 4;
  bf16x4 o;
#pragma unroll
  for (int i = 0; i < 4; ++i) o[i] = (__bf16)LT[n * 33 + kc + i];
  *(bf16x4*)&WT[(size_t)p * (HH * EE) + (size_t)(nb + n) * EE + kb + kc] = o;
}

// ---------------------------------------------------------------------------
// Kernel 1: QKV projection. Grid (256,3) = 768 blocks (3/CU), block 256 = 4
// waves. BM=32, BN=128, BK=64 single-buffered LDS (23 KB) with REGISTER
// prefetch of the next k-tile during compute. Wave = 32m x 32n (2x2 frags),
// 8 MFMA/step, 16 steps. q scaled by QSCALE; v written transposed vT[b][d][s].
// ---------------------------------------------------------------------------
__global__ __launch_bounds__(256, 4) void qkv_proj(
    const float* __restrict__ x, const __bf16* __restrict__ WT,
    __bf16* __restrict__ qkv) {
  __shared__ __align__(16) __bf16 xs[32 * 72];    // 32 rows x 64 k (+8 pad)
  __shared__ __align__(16) __bf16 wsd[128 * 72];  // 128 n x 64 k (+8 pad)

  const int t = threadIdx.x, w = t >> 6, lane = t & 63;
  const int quad = lane >> 4, l16 = lane & 15;
  const int mb = blockIdx.x * 32;
  const int proj = blockIdx.y;
  const __bf16* __restrict__ WTp = WT + (size_t)proj * (HH * EE);

  // staging coords
  const int xrow0 = t >> 4, xkc0 = (t & 15) * 4;            // i in {0,1}: +16 rows
  const int wn0 = t >> 3, wkc0 = (t & 7) * 8;               // i in {0..3}: +32 n

  f32x4 acc[2][2];
#pragma unroll
  for (int i = 0; i < 2; ++i)
#pragma unroll
    for (int j = 0; j < 2; ++j) acc[i][j] = (f32x4){0.f, 0.f, 0.f, 0.f};

  float4 xr[2];
  bf16x8 wr[4];
  // prologue: load k-tile 0 into regs
#pragma unroll
  for (int i = 0; i < 2; ++i)
    xr[i] = *(const float4*)&x[(size_t)(mb + xrow0 + i * 16) * EE + xkc0];
#pragma unroll
  for (int i = 0; i < 4; ++i)
    wr[i] = *(const bf16x8*)&WTp[(size_t)(wn0 + i * 32) * EE + wkc0];

  for (int kt = 0; kt < 16; ++kt) {
    __syncthreads();  // previous tile's ds_reads complete
#pragma unroll
    for (int i = 0; i < 2; ++i) {
      bf16x4 bv;
      bv[0] = (__bf16)xr[i].x; bv[1] = (__bf16)xr[i].y;
      bv[2] = (__bf16)xr[i].z; bv[3] = (__bf16)xr[i].w;
      *(bf16x4*)&xs[(xrow0 + i * 16) * 72 + xkc0] = bv;
    }
#pragma unroll
    for (int i = 0; i < 4; ++i)
      *(bf16x8*)&wsd[(wn0 + i * 32) * 72 + wkc0] = wr[i];
    __syncthreads();

    if (kt < 15) {  // prefetch next tile into regs (in flight during compute)
      const int kb = (kt + 1) * 64;
#pragma unroll
      for (int i = 0; i < 2; ++i)
        xr[i] = *(const float4*)&x[(size_t)(mb + xrow0 + i * 16) * EE + kb + xkc0];
#pragma unroll
      for (int i = 0; i < 4; ++i)
        wr[i] = *(const bf16x8*)&WTp[(size_t)(wn0 + i * 32) * EE + kb + wkc0];
    }

    bf16x8 af[2][2], bfr[2][2];
#pragma unroll
    for (int mi = 0; mi < 2; ++mi)
#pragma unroll
      for (int kc = 0; kc < 2; ++kc)
        af[mi][kc] = *(const bf16x8*)&xs[(mi * 16 + l16) * 72 + kc * 32 + quad * 8];
#pragma unroll
    for (int ni = 0; ni < 2; ++ni)
#pragma unroll
      for (int kc = 0; kc < 2; ++kc)
        bfr[ni][kc] =
            *(const bf16x8*)&wsd[(w * 32 + ni * 16 + l16) * 72 + kc * 32 + quad * 8];
#pragma unroll
    for (int kc = 0; kc < 2; ++kc)
#pragma unroll
      for (int mi = 0; mi < 2; ++mi)
#pragma unroll
        for (int ni = 0; ni < 2; ++ni)
          acc[mi][ni] = __builtin_amdgcn_mfma_f32_16x16x32_bf16(
              af[mi][kc], bfr[ni][kc], acc[mi][ni], 0, 0, 0);
  }

  if (proj < 2) {
    const float scale = (proj == 0) ? QSCALE : 1.0f;
    __bf16* outp = qkv + (size_t)proj * PLANE;
#pragma unroll
    for (int mi = 0; mi < 2; ++mi) {
      const int srow = mb + mi * 16 + quad * 4;
#pragma unroll
      for (int ni = 0; ni < 2; ++ni) {
        const int col = w * 32 + ni * 16 + l16;
#pragma unroll
        for (int rr = 0; rr < 4; ++rr)
          outp[(size_t)(srow + rr) * HH + col] = (__bf16)(acc[mi][ni][rr] * scale);
      }
    }
  } else {
    __bf16* vtp = qkv + 2 * (size_t)PLANE;
#pragma unroll
    for (int mi = 0; mi < 2; ++mi) {
      const int srow = mb + mi * 16 + quad * 4;
      const int bb = srow >> 11, sl = srow & 2047;
#pragma unroll
      for (int ni = 0; ni < 2; ++ni) {
        const int d = w * 32 + ni * 16 + l16;
        bf16x4 vv;
#pragma unroll
        for (int rr = 0; rr < 4; ++rr) vv[rr] = (__bf16)acc[mi][ni][rr];
        *(bf16x4*)&vtp[(size_t)bb * BPLANE + (size_t)d * SS + sl] = vv;
      }
    }
  }
}

// ---------------------------------------------------------------------------
// Kernel 2: causal attention. Block = (b, 64 q-rows, 128-k chunk): 1088
// blocks (4.25/CU), single-buffer LDS (35.8 KB, 3 blocks/CU by VGPR) with
// register prefetch across the barrier. K rows stored lambda-permuted so the
// S^T trick (C-layout == PV A-fragment) uses standard column ds_reads.
// Wave = 16 q-rows. Tiles 0,1 (single chunk) write fp32 out; else bf16
// partials + l for attn_merge.
// ---------------------------------------------------------------------------
__global__ __launch_bounds__(256, 3) void flash_attn_mfma(
    const __bf16* __restrict__ qkv, float* __restrict__ out,
    __bf16* __restrict__ Opart, float* __restrict__ lpart) {
  __shared__ __align__(16) __bf16 K_s[64 * 136];
  __shared__ __align__(16) __bf16 VT_s[128 * 72];

  const int t = threadIdx.x, w = t >> 6, lane = t & 63;
  const int quad = lane >> 4, l16 = lane & 15;
  const int b = blockIdx.x & 3;
  const int r = (AUNITS - 1) - (blockIdx.x >> 2);  // heavy-first
  // find tile tt with P(tt) <= r < P(tt+1), P(t) = floor((t+1)^2/4)
  int tt = 0;
  while ((((tt + 2) * (tt + 2)) >> 2) <= r) ++tt;
  const int c = r - (((tt + 1) * (tt + 1)) >> 2);
  const int qrb = tt * 64;
  const int k0 = c * 128;
  const int kend = min(k0 + 128, qrb + 64);
  const int ntiles = (kend - k0) >> 6;  // 1 or 2
  const int qsb = qrb + w * 16;

  const size_t bq = (size_t)b * BPLANE;
  const __bf16* __restrict__ qp = qkv + bq;
  const __bf16* __restrict__ kp = qkv + PLANE + bq;
  const __bf16* __restrict__ vt = qkv + 2 * (size_t)PLANE + bq;  // [d][s]

  bf16x8 qf[4];
#pragma unroll
  for (int cc = 0; cc < 4; ++cc)
    qf[cc] = *(const bf16x8*)&qp[(size_t)(qsb + l16) * HH + cc * 32 + quad * 8];

  f32x4 of[8];
#pragma unroll
  for (int f = 0; f < 8; ++f) of[f] = (f32x4){0.f, 0.f, 0.f, 0.f};
  float lp = 0.f;  // per lane: q = qsb + l16

  // staging coords
  const int krow = t >> 2, kdc = (t & 3) * 8;        // i in {0..3}: +... (see below)
  bf16x8 krg[4], vrg[4];
  // prologue: load k-tile 0 into regs
#pragma unroll
  for (int i = 0; i < 4; ++i) {
    const int idx = t + i * 256;
    const int row = idx >> 4, dc = (idx & 15) * 8;
    krg[i] = *(const bf16x8*)&kp[(size_t)(k0 + row) * HH + dc];
  }
#pragma unroll
  for (int i = 0; i < 4; ++i) {
    const int idx = t + i * 256;
    const int d = idx >> 3, kc = (idx & 7) * 8;
    vrg[i] = *(const bf16x8*)&vt[(size_t)d * SS + k0 + kc];
  }

  for (int jt = 0; jt < ntiles; ++jt) {
    __syncthreads();  // previous tile's ds_reads complete
#pragma unroll
    for (int i = 0; i < 4; ++i) {
      const int idx = t + i * 256;
      const int row = idx >> 4, dc = (idx & 15) * 8;
      const int lam = (row & 32) + ((row & 4) ? 16 : 0) +
                      (((row & 31) >> 3) << 2) + (row & 3);
      *(bf16x8*)&K_s[lam * 136 + dc] = krg[i];
    }
#pragma unroll
    for (int i = 0; i < 4; ++i) {
      const int idx = t + i * 256;
      const int d = idx >> 3, kc = (idx & 7) * 8;
      *(bf16x8*)&VT_s[d * 72 + kc] = vrg[i];
    }
    __syncthreads();

    if (jt + 1 < ntiles) {  // prefetch next tile into regs
      const int kb2 = k0 + (jt + 1) * 64;
#pragma unroll
      for (int i = 0; i < 4; ++i) {
        const int idx = t + i * 256;
        const int row = idx >> 4, dc = (idx & 15) * 8;
        krg[i] = *(const bf16x8*)&kp[(size_t)(kb2 + row) * HH + dc];
      }
#pragma unroll
      for (int i = 0; i < 4; ++i) {
        const int idx = t + i * 256;
        const int d = idx >> 3, kc = (idx & 7) * 8;
        vrg[i] = *(const bf16x8*)&vt[(size_t)d * SS + kb2 + kc];
      }
    }

#pragma unroll
    for (int s32 = 0; s32 < 2; ++s32) {
      const int kabs = k0 + jt * 64 + s32 * 32;
      if (kabs <= qsb + 15) {  // wave-uniform: skip fully-masked steps
        bf16x8 ku[4], kv[4];
#pragma unroll
        for (int cc = 0; cc < 4; ++cc) {
          ku[cc] = *(const bf16x8*)&K_s[(s32 * 32 + l16) * 136 + cc * 32 + quad * 8];
          kv[cc] = *(const bf16x8*)&K_s[(s32 * 32 + 16 + l16) * 136 + cc * 32 + quad * 8];
        }
        f32x4 su = (f32x4){0.f, 0.f, 0.f, 0.f};
        f32x4 sv = (f32x4){0.f, 0.f, 0.f, 0.f};
#pragma unroll
        for (int cc = 0; cc < 4; ++cc) {
          su = __builtin_amdgcn_mfma_f32_16x16x32_bf16(ku[cc], qf[cc], su, 0, 0, 0);
          sv = __builtin_amdgcn_mfma_f32_16x16x32_bf16(kv[cc], qf[cc], sv, 0, 0, 0);
        }
        const int qg = qsb + l16;
        bf16x8 pa;
#pragma unroll
        for (int rr = 0; rr < 4; ++rr) {
          const int kU = kabs + quad * 8 + rr;
          const float eU = (kU <= qg) ? exp2f(su[rr]) : 0.f;
          const float eV = (kU + 4 <= qg) ? exp2f(sv[rr]) : 0.f;
          pa[rr] = (__bf16)eU;
          pa[4 + rr] = (__bf16)eV;
          lp += eU + eV;
        }
#pragma unroll
        for (int f = 0; f < 8; ++f) {
          const bf16x8 vb =
              *(const bf16x8*)&VT_s[(f * 16 + l16) * 72 + s32 * 32 + quad * 8];
          of[f] = __builtin_amdgcn_mfma_f32_16x16x32_bf16(pa, vb, of[f], 0, 0, 0);
        }
      }
    }
  }

  // reduce l across quads (lane q = l16)
  lp += __shfl_xor(lp, 16);
  lp += __shfl_xor(lp, 32);

  if (tt < 2) {  // single chunk: finalize (O rows q = quad*4+rr)
#pragma unroll
    for (int rr = 0; rr < 4; ++rr) {
      const float lrow = __shfl(lp, quad * 4 + rr);
      const float inv = 1.0f / lrow;
#pragma unroll
      for (int f = 0; f < 8; ++f)
        out[bq + (size_t)(qsb + quad * 4 + rr) * HH + f * 16 + l16] =
            of[f][rr] * inv;
    }
  } else {
    const int u = b * AUNITS + r;
    __bf16* op = Opart + (size_t)u * 8192;
#pragma unroll
    for (int f = 0; f < 8; ++f)
#pragma unroll
      for (int rr = 0; rr < 4; ++rr)
        op[(w * 16 + quad * 4 + rr) * 128 + f * 16 + l16] = (__bf16)of[f][rr];
    if (quad == 0) lpart[u * 64 + w * 16 + l16] = lp;
  }
}

// ---------------------------------------------------------------------------
// Kernel 3: merge chunk partials for 64-row tiles 2..31. Grid 4*30 blocks.
// ---------------------------------------------------------------------------
__global__ __launch_bounds__(256) void attn_merge(
    const __bf16* __restrict__ Opart, const float* __restrict__ lpart,
    float* __restrict__ out) {
  const int b = blockIdx.x / 30;
  const int tile = 2 + (blockIdx.x % 30);
  const int nc = (tile + 2) >> 1;  // ceil((tile+1)/2)
  const int u0 = b * AUNITS + (((tile + 1) * (tile + 1)) >> 2);
  const int t = threadIdx.x;
#pragma unroll
  for (int i = 0; i < 4; ++i) {
    const int idx = t + i * 256;
    const int e0 = idx * 8;
    const int row = idx >> 4;
    float acc[8] = {0.f, 0.f, 0.f, 0.f, 0.f, 0.f, 0.f, 0.f};
    float lsum = 0.f;
    for (int cc = 0; cc < nc; ++cc) {
      const bf16x8 pv = *(const bf16x8*)&Opart[(size_t)(u0 + cc) * 8192 + e0];
#pragma unroll
      for (int k = 0; k < 8; ++k) acc[k] += (float)pv[k];
      lsum += lpart[(u0 + cc) * 64 + row];
    }
    const float inv = 1.0f / lsum;
    float4 r0, r1;
    r0.x = acc[0] * inv; r0.y = acc[1] * inv; r0.z = acc[2] * inv; r0.w = acc[3] * inv;
    r1.x = acc[4] * inv; r1.y = acc[5] * inv; r1.z = acc[6] * inv; r1.w = acc[7] * inv;
    float* op = out + (size_t)b * BPLANE + (size_t)tile * 8192 + e0;
    ((float4*)op)[0] = r0;
    ((float4*)op)[1] = r1;
  }
}

extern "C" void kernel_launch(void* const* d_in, const int* in_sizes, int n_in,
                              void* d_out, int out_size, void* d_ws, size_t ws_size,
                              hipStream_t stream) {
  const float* x  = (const float*)d_in[0];
  const float* Wq = (const float*)d_in[1];
  const float* Wk = (const float*)d_in[2];
  const float* Wv = (const float*)d_in[3];
  float* out = (float*)d_out;

  // ws: qkv bf16 6.29MB | WT bf16 0.79MB | Opart bf16 17.8MB | lpart 0.28MB
  char* wsb = (char*)d_ws;
  __bf16* qkv = (__bf16*)wsb;
  __bf16* WT = (__bf16*)(wsb + (size_t)3 * PLANE * 2);
  __bf16* Opart = (__bf16*)(wsb + (size_t)3 * PLANE * 2 + (size_t)3 * HH * EE * 2);
  float* lpart = (float*)(wsb + (size_t)3 * PLANE * 2 + (size_t)3 * HH * EE * 2 +
                          (size_t)BB * AUNITS * 8192 * 2);

  prep_w<<<384, 256, 0, stream>>>(Wq, Wk, Wv, WT);
  qkv_proj<<<dim3(BB * SS / 32, 3), 256, 0, stream>>>(x, WT, qkv);
  flash_attn_mfma<<<BB * AUNITS, 256, 0, stream>>>(qkv, out, Opart, lpart);
  attn_merge<<<BB * 30, 256, 0, stream>>>(Opart, lpart, out);
}

// Round 9
// 114.894 us; speedup vs baseline: 1.5863x; 1.1230x over previous
//
#include <hip/hip_runtime.h>
#include <hip/hip_cooperative_groups.h>
#include <math.h>

namespace cg = cooperative_groups;

// B,S,E,H = 4,2048,1024,128
#define BB 4
#define SS 2048
#define EE 1024
#define HH 128
#define PLANE (BB * SS * HH)
#define BPLANE (SS * HH)
#define UPB_C 187          // coop: units/batch, 192-k chunks: sum ceil((t+1)/3)
#define NU_C (UPB_C * 4)   // 748
#define NBLK_C 512
#define AUNITS 272         // fallback: units/batch, 128-k chunks

typedef __bf16 bf16x8 __attribute__((ext_vector_type(8)));
typedef __bf16 bf16x4 __attribute__((ext_vector_type(4)));
typedef float f32x4 __attribute__((ext_vector_type(4)));

#define QSCALE (0.08838834764831845f * 1.4426950408889634f)  // 1/sqrt(H)*log2e

// ===========================================================================
// COOPERATIVE single-kernel path: 512 blocks x 256 thr, 4 phases.
// Bodies verbatim from the R7-passing kernels; blocks loop over units.
// ===========================================================================
__global__ __launch_bounds__(256, 2) void fused_head(
    const float* __restrict__ x, const float* __restrict__ Wq,
    const float* __restrict__ Wk, const float* __restrict__ Wv,
    __bf16* __restrict__ qkv, __bf16* __restrict__ WT,
    __bf16* __restrict__ Opart, float* __restrict__ lpart,
    float* __restrict__ out) {
  cg::grid_group grid = cg::this_grid();
  __shared__ __align__(16) char smem[35840];

  const int t = threadIdx.x, w = t >> 6, lane = t & 63;
  const int quad = lane >> 4, l16 = lane & 15;
  const int u = blockIdx.x;

  // ======================= Phase 0: W transpose (384 units) ==============
  if (u < 384) {
    float* LT = (float*)smem;  // 32 x 33 fp32
    const int p = u >> 7;
    const int r0 = u & 127;
    const int kb = (r0 >> 2) * 32, nb = (r0 & 3) * 32;
    const float* __restrict__ W = (p == 0) ? Wq : (p == 1) ? Wk : Wv;
    const int kr = t >> 3, nc4 = (t & 7) * 4;
    const float4 v = *(const float4*)&W[(size_t)(kb + kr) * HH + nb + nc4];
    LT[(nc4 + 0) * 33 + kr] = v.x;
    LT[(nc4 + 1) * 33 + kr] = v.y;
    LT[(nc4 + 2) * 33 + kr] = v.z;
    LT[(nc4 + 3) * 33 + kr] = v.w;
    __syncthreads();
    const int n = t >> 3, kc = (t & 7) * 4;
    bf16x4 o;
#pragma unroll
    for (int i = 0; i < 4; ++i) o[i] = (__bf16)LT[n * 33 + kc + i];
    *(bf16x4*)&WT[(size_t)p * (HH * EE) + (size_t)(nb + n) * EE + kb + kc] = o;
  }
  __threadfence();
  grid.sync();

  // ======================= Phase 1: QKV projection (768 units) ===========
  for (int uu = u; uu < 768; uu += NBLK_C) {
    __bf16* xs = (__bf16*)smem;            // 32 rows x 64 k (stride 72)
    __bf16* wsd = (__bf16*)(smem + 4608);  // 128 n x 64 k (stride 72)
    const int mb = (uu & 255) * 32;
    const int proj = uu >> 8;
    const __bf16* __restrict__ WTp = WT + (size_t)proj * (HH * EE);

    const int xrow0 = t >> 4, xkc0 = (t & 15) * 4;
    const int wn0 = t >> 3, wkc0 = (t & 7) * 8;

    f32x4 acc[2][2];
#pragma unroll
    for (int i = 0; i < 2; ++i)
#pragma unroll
      for (int j = 0; j < 2; ++j) acc[i][j] = (f32x4){0.f, 0.f, 0.f, 0.f};

    float4 xr[2];
    bf16x8 wr[4];
#pragma unroll
    for (int i = 0; i < 2; ++i)
      xr[i] = *(const float4*)&x[(size_t)(mb + xrow0 + i * 16) * EE + xkc0];
#pragma unroll
    for (int i = 0; i < 4; ++i)
      wr[i] = *(const bf16x8*)&WTp[(size_t)(wn0 + i * 32) * EE + wkc0];

    for (int kt = 0; kt < 16; ++kt) {
      __syncthreads();
#pragma unroll
      for (int i = 0; i < 2; ++i) {
        bf16x4 bv;
        bv[0] = (__bf16)xr[i].x; bv[1] = (__bf16)xr[i].y;
        bv[2] = (__bf16)xr[i].z; bv[3] = (__bf16)xr[i].w;
        *(bf16x4*)&xs[(xrow0 + i * 16) * 72 + xkc0] = bv;
      }
#pragma unroll
      for (int i = 0; i < 4; ++i)
        *(bf16x8*)&wsd[(wn0 + i * 32) * 72 + wkc0] = wr[i];
      __syncthreads();

      if (kt < 15) {
        const int kb = (kt + 1) * 64;
#pragma unroll
        for (int i = 0; i < 2; ++i)
          xr[i] = *(const float4*)&x[(size_t)(mb + xrow0 + i * 16) * EE + kb + xkc0];
#pragma unroll
        for (int i = 0; i < 4; ++i)
          wr[i] = *(const bf16x8*)&WTp[(size_t)(wn0 + i * 32) * EE + kb + wkc0];
      }

      bf16x8 af[2][2], bfr[2][2];
#pragma unroll
      for (int mi = 0; mi < 2; ++mi)
#pragma unroll
        for (int kc = 0; kc < 2; ++kc)
          af[mi][kc] = *(const bf16x8*)&xs[(mi * 16 + l16) * 72 + kc * 32 + quad * 8];
#pragma unroll
      for (int ni = 0; ni < 2; ++ni)
#pragma unroll
        for (int kc = 0; kc < 2; ++kc)
          bfr[ni][kc] =
              *(const bf16x8*)&wsd[(w * 32 + ni * 16 + l16) * 72 + kc * 32 + quad * 8];
#pragma unroll
      for (int kc = 0; kc < 2; ++kc)
#pragma unroll
        for (int mi = 0; mi < 2; ++mi)
#pragma unroll
          for (int ni = 0; ni < 2; ++ni)
            acc[mi][ni] = __builtin_amdgcn_mfma_f32_16x16x32_bf16(
                af[mi][kc], bfr[ni][kc], acc[mi][ni], 0, 0, 0);
    }

    if (proj < 2) {
      const float scale = (proj == 0) ? QSCALE : 1.0f;
      __bf16* outp = qkv + (size_t)proj * PLANE;
#pragma unroll
      for (int mi = 0; mi < 2; ++mi) {
        const int srow = mb + mi * 16 + quad * 4;
#pragma unroll
        for (int ni = 0; ni < 2; ++ni) {
          const int col = w * 32 + ni * 16 + l16;
#pragma unroll
          for (int rr = 0; rr < 4; ++rr)
            outp[(size_t)(srow + rr) * HH + col] = (__bf16)(acc[mi][ni][rr] * scale);
        }
      }
    } else {
      __bf16* vtp = qkv + 2 * (size_t)PLANE;
#pragma unroll
      for (int mi = 0; mi < 2; ++mi) {
        const int srow = mb + mi * 16 + quad * 4;
        const int bb2 = srow >> 11, sl = srow & 2047;
#pragma unroll
        for (int ni = 0; ni < 2; ++ni) {
          const int d = w * 32 + ni * 16 + l16;
          bf16x4 vv;
#pragma unroll
          for (int rr = 0; rr < 4; ++rr) vv[rr] = (__bf16)acc[mi][ni][rr];
          *(bf16x4*)&vtp[(size_t)bb2 * BPLANE + (size_t)d * SS + sl] = vv;
        }
      }
    }
    __syncthreads();
  }
  __threadfence();
  grid.sync();

  // ======================= Phase 2: causal attention (748 units) =========
  for (int uu = u; uu < NU_C; uu += NBLK_C) {
    __bf16* K_s = (__bf16*)smem;             // 64 x 136
    __bf16* VT_s = (__bf16*)(smem + 17408);  // 128 x 72
    const int ur = (NU_C - 1) - uu;  // heavy-first
    const int b = ur & 3;
    const int r = ur >> 2;  // 0..186
    int tt = 0, Pp = 0;
    for (;;) {
      const int n = (tt + 3) / 3;  // chunks for tile tt
      if (r < Pp + n) break;
      Pp += n;
      ++tt;
    }
    const int c = r - Pp;
    const int qrb = tt * 64;
    const int k0 = c * 192;
    const int kend = min(k0 + 192, qrb + 64);
    const int ntiles = (kend - k0 + 63) >> 6;  // 1..3
    const int qsb = qrb + w * 16;

    const size_t bq = (size_t)b * BPLANE;
    const __bf16* __restrict__ qp = qkv + bq;
    const __bf16* __restrict__ kp = qkv + PLANE + bq;
    const __bf16* __restrict__ vt = qkv + 2 * (size_t)PLANE + bq;  // [d][s]

    bf16x8 qf[4];
#pragma unroll
    for (int cc = 0; cc < 4; ++cc)
      qf[cc] = *(const bf16x8*)&qp[(size_t)(qsb + l16) * HH + cc * 32 + quad * 8];

    f32x4 of[8];
#pragma unroll
    for (int f = 0; f < 8; ++f) of[f] = (f32x4){0.f, 0.f, 0.f, 0.f};
    float lp = 0.f;  // per lane: q = qsb + l16

    bf16x8 krg[4], vrg[4];
#pragma unroll
    for (int i = 0; i < 4; ++i) {
      const int idx = t + i * 256;
      const int row = idx >> 4, dc = (idx & 15) * 8;
      krg[i] = *(const bf16x8*)&kp[(size_t)(k0 + row) * HH + dc];
    }
#pragma unroll
    for (int i = 0; i < 4; ++i) {
      const int idx = t + i * 256;
      const int d = idx >> 3, kc = (idx & 7) * 8;
      vrg[i] = *(const bf16x8*)&vt[(size_t)d * SS + k0 + kc];
    }

    for (int jt = 0; jt < ntiles; ++jt) {
      __syncthreads();
#pragma unroll
      for (int i = 0; i < 4; ++i) {
        const int idx = t + i * 256;
        const int row = idx >> 4, dc = (idx & 15) * 8;
        const int lam = (row & 32) + ((row & 4) ? 16 : 0) +
                        (((row & 31) >> 3) << 2) + (row & 3);
        *(bf16x8*)&K_s[lam * 136 + dc] = krg[i];
      }
#pragma unroll
      for (int i = 0; i < 4; ++i) {
        const int idx = t + i * 256;
        const int d = idx >> 3, kc = (idx & 7) * 8;
        *(bf16x8*)&VT_s[d * 72 + kc] = vrg[i];
      }
      __syncthreads();

      if (jt + 1 < ntiles) {
        const int kb2 = k0 + (jt + 1) * 64;
#pragma unroll
        for (int i = 0; i < 4; ++i) {
          const int idx = t + i * 256;
          const int row = idx >> 4, dc = (idx & 15) * 8;
          krg[i] = *(const bf16x8*)&kp[(size_t)(kb2 + row) * HH + dc];
        }
#pragma unroll
        for (int i = 0; i < 4; ++i) {
          const int idx = t + i * 256;
          const int d = idx >> 3, kc = (idx & 7) * 8;
          vrg[i] = *(const bf16x8*)&vt[(size_t)d * SS + kb2 + kc];
        }
      }

#pragma unroll
      for (int s32 = 0; s32 < 2; ++s32) {
        const int kabs = k0 + jt * 64 + s32 * 32;
        if (kabs <= qsb + 15) {  // wave-uniform skip of fully-masked steps
          bf16x8 ku[4], kv[4];
#pragma unroll
          for (int cc = 0; cc < 4; ++cc) {
            ku[cc] = *(const bf16x8*)&K_s[(s32 * 32 + l16) * 136 + cc * 32 + quad * 8];
            kv[cc] = *(const bf16x8*)&K_s[(s32 * 32 + 16 + l16) * 136 + cc * 32 + quad * 8];
          }
          f32x4 su = (f32x4){0.f, 0.f, 0.f, 0.f};
          f32x4 sv = (f32x4){0.f, 0.f, 0.f, 0.f};
#pragma unroll
          for (int cc = 0; cc < 4; ++cc) {
            su = __builtin_amdgcn_mfma_f32_16x16x32_bf16(ku[cc], qf[cc], su, 0, 0, 0);
            sv = __builtin_amdgcn_mfma_f32_16x16x32_bf16(kv[cc], qf[cc], sv, 0, 0, 0);
          }
          const int qg = qsb + l16;
          bf16x8 pa;
#pragma unroll
          for (int rr = 0; rr < 4; ++rr) {
            const int kU = kabs + quad * 8 + rr;
            const float eU = (kU <= qg) ? exp2f(su[rr]) : 0.f;
            const float eV = (kU + 4 <= qg) ? exp2f(sv[rr]) : 0.f;
            pa[rr] = (__bf16)eU;
            pa[4 + rr] = (__bf16)eV;
            lp += eU + eV;
          }
#pragma unroll
          for (int f = 0; f < 8; ++f) {
            const bf16x8 vb =
                *(const bf16x8*)&VT_s[(f * 16 + l16) * 72 + s32 * 32 + quad * 8];
            of[f] = __builtin_amdgcn_mfma_f32_16x16x32_bf16(pa, vb, of[f], 0, 0, 0);
          }
        }
      }
    }

    lp += __shfl_xor(lp, 16);
    lp += __shfl_xor(lp, 32);

    if (tt < 3) {  // single chunk: finalize directly
#pragma unroll
      for (int rr = 0; rr < 4; ++rr) {
        const float lrow = __shfl(lp, quad * 4 + rr);
        const float inv = 1.0f / lrow;
#pragma unroll
        for (int f = 0; f < 8; ++f)
          out[bq + (size_t)(qsb + quad * 4 + rr) * HH + f * 16 + l16] =
              of[f][rr] * inv;
      }
    } else {
      const int us = b * UPB_C + r;
      __bf16* op = Opart + (size_t)us * 8192;
#pragma unroll
      for (int f = 0; f < 8; ++f)
#pragma unroll
        for (int rr = 0; rr < 4; ++rr)
          op[(w * 16 + quad * 4 + rr) * 128 + f * 16 + l16] = (__bf16)of[f][rr];
      if (quad == 0) lpart[us * 64 + w * 16 + l16] = lp;
    }
    __syncthreads();
  }
  __threadfence();
  grid.sync();

  // ======================= Phase 3: merge (464 units) ====================
  if (u < 464) {
    const int q4 = u & 3;
    const int m = u >> 2;  // 0..115
    const int b = m / 29;
    const int tile = 3 + (m % 29);
    const int nc = (tile + 3) / 3;
    int Pp = 0;
    for (int j = 0; j < tile; ++j) Pp += (j + 3) / 3;
    const int u0 = b * UPB_C + Pp;
    const int idx = q4 * 256 + t;
    const int e0 = idx * 8;
    const int row = idx >> 4;
    float acc[8] = {0.f, 0.f, 0.f, 0.f, 0.f, 0.f, 0.f, 0.f};
    float lsum = 0.f;
    for (int cc = 0; cc < nc; ++cc) {
      const bf16x8 pv = *(const bf16x8*)&Opart[(size_t)(u0 + cc) * 8192 + e0];
#pragma unroll
      for (int k = 0; k < 8; ++k) acc[k] += (float)pv[k];
      lsum += lpart[(u0 + cc) * 64 + row];
    }
    const float inv = 1.0f / lsum;
    float4 r0, r1;
    r0.x = acc[0] * inv; r0.y = acc[1] * inv; r0.z = acc[2] * inv; r0.w = acc[3] * inv;
    r1.x = acc[4] * inv; r1.y = acc[5] * inv; r1.z = acc[6] * inv; r1.w = acc[7] * inv;
    float* op = out + (size_t)b * BPLANE + (size_t)tile * 8192 + e0;
    ((float4*)op)[0] = r0;
    ((float4*)op)[1] = r1;
  }
}

// ===========================================================================
// FALLBACK path: the R7-verified 4-kernel pipeline (merge split 4x wider).
// ===========================================================================
__global__ __launch_bounds__(256) void prep_w(
    const float* __restrict__ Wq, const float* __restrict__ Wk,
    const float* __restrict__ Wv, __bf16* __restrict__ WT) {
  __shared__ float LT[32 * 33];
  const int p = blockIdx.x >> 7;
  const int r = blockIdx.x & 127;
  const int kb = (r >> 2) * 32, nb = (r & 3) * 32;
  const float* __restrict__ W = (p == 0) ? Wq : (p == 1) ? Wk : Wv;
  const int t = threadIdx.x;
  const int kr = t >> 3, nc4 = (t & 7) * 4;
  const float4 v = *(const float4*)&W[(size_t)(kb + kr) * HH + nb + nc4];
  LT[(nc4 + 0) * 33 + kr] = v.x;
  LT[(nc4 + 1) * 33 + kr] = v.y;
  LT[(nc4 + 2) * 33 + kr] = v.z;
  LT[(nc4 + 3) * 33 + kr] = v.w;
  __syncthreads();
  const int n = t >> 3, kc = (t & 7) * 4;
  bf16x4 o;
#pragma unroll
  for (int i = 0; i < 4; ++i) o[i] = (__bf16)LT[n * 33 + kc + i];
  *(bf16x4*)&WT[(size_t)p * (HH * EE) + (size_t)(nb + n) * EE + kb + kc] = o;
}

__global__ __launch_bounds__(256, 4) void qkv_proj(
    const float* __restrict__ x, const __bf16* __restrict__ WT,
    __bf16* __restrict__ qkv) {
  __shared__ __align__(16) __bf16 xs[32 * 72];
  __shared__ __align__(16) __bf16 wsd[128 * 72];

  const int t = threadIdx.x, w = t >> 6, lane = t & 63;
  const int quad = lane >> 4, l16 = lane & 15;
  const int mb = blockIdx.x * 32;
  const int proj = blockIdx.y;
  const __bf16* __restrict__ WTp = WT + (size_t)proj * (HH * EE);

  const int xrow0 = t >> 4, xkc0 = (t & 15) * 4;
  const int wn0 = t >> 3, wkc0 = (t & 7) * 8;

  f32x4 acc[2][2];
#pragma unroll
  for (int i = 0; i < 2; ++i)
#pragma unroll
    for (int j = 0; j < 2; ++j) acc[i][j] = (f32x4){0.f, 0.f, 0.f, 0.f};

  float4 xr[2];
  bf16x8 wr[4];
#pragma unroll
  for (int i = 0; i < 2; ++i)
    xr[i] = *(const float4*)&x[(size_t)(mb + xrow0 + i * 16) * EE + xkc0];
#pragma unroll
  for (int i = 0; i < 4; ++i)
    wr[i] = *(const bf16x8*)&WTp[(size_t)(wn0 + i * 32) * EE + wkc0];

  for (int kt = 0; kt < 16; ++kt) {
    __syncthreads();
#pragma unroll
    for (int i = 0; i < 2; ++i) {
      bf16x4 bv;
      bv[0] = (__bf16)xr[i].x; bv[1] = (__bf16)xr[i].y;
      bv[2] = (__bf16)xr[i].z; bv[3] = (__bf16)xr[i].w;
      *(bf16x4*)&xs[(xrow0 + i * 16) * 72 + xkc0] = bv;
    }
#pragma unroll
    for (int i = 0; i < 4; ++i)
      *(bf16x8*)&wsd[(wn0 + i * 32) * 72 + wkc0] = wr[i];
    __syncthreads();

    if (kt < 15) {
      const int kb = (kt + 1) * 64;
#pragma unroll
      for (int i = 0; i < 2; ++i)
        xr[i] = *(const float4*)&x[(size_t)(mb + xrow0 + i * 16) * EE + kb + xkc0];
#pragma unroll
      for (int i = 0; i < 4; ++i)
        wr[i] = *(const bf16x8*)&WTp[(size_t)(wn0 + i * 32) * EE + kb + wkc0];
    }

    bf16x8 af[2][2], bfr[2][2];
#pragma unroll
    for (int mi = 0; mi < 2; ++mi)
#pragma unroll
      for (int kc = 0; kc < 2; ++kc)
        af[mi][kc] = *(const bf16x8*)&xs[(mi * 16 + l16) * 72 + kc * 32 + quad * 8];
#pragma unroll
    for (int ni = 0; ni < 2; ++ni)
#pragma unroll
      for (int kc = 0; kc < 2; ++kc)
        bfr[ni][kc] =
            *(const bf16x8*)&wsd[(w * 32 + ni * 16 + l16) * 72 + kc * 32 + quad * 8];
#pragma unroll
    for (int kc = 0; kc < 2; ++kc)
#pragma unroll
      for (int mi = 0; mi < 2; ++mi)
#pragma unroll
        for (int ni = 0; ni < 2; ++ni)
          acc[mi][ni] = __builtin_amdgcn_mfma_f32_16x16x32_bf16(
              af[mi][kc], bfr[ni][kc], acc[mi][ni], 0, 0, 0);
  }

  if (proj < 2) {
    const float scale = (proj == 0) ? QSCALE : 1.0f;
    __bf16* outp = qkv + (size_t)proj * PLANE;
#pragma unroll
    for (int mi = 0; mi < 2; ++mi) {
      const int srow = mb + mi * 16 + quad * 4;
#pragma unroll
      for (int ni = 0; ni < 2; ++ni) {
        const int col = w * 32 + ni * 16 + l16;
#pragma unroll
        for (int rr = 0; rr < 4; ++rr)
          outp[(size_t)(srow + rr) * HH + col] = (__bf16)(acc[mi][ni][rr] * scale);
      }
    }
  } else {
    __bf16* vtp = qkv + 2 * (size_t)PLANE;
#pragma unroll
    for (int mi = 0; mi < 2; ++mi) {
      const int srow = mb + mi * 16 + quad * 4;
      const int bb2 = srow >> 11, sl = srow & 2047;
#pragma unroll
      for (int ni = 0; ni < 2; ++ni) {
        const int d = w * 32 + ni * 16 + l16;
        bf16x4 vv;
#pragma unroll
        for (int rr = 0; rr < 4; ++rr) vv[rr] = (__bf16)acc[mi][ni][rr];
        *(bf16x4*)&vtp[(size_t)bb2 * BPLANE + (size_t)d * SS + sl] = vv;
      }
    }
  }
}

__global__ __launch_bounds__(256, 3) void flash_attn_mfma(
    const __bf16* __restrict__ qkv, float* __restrict__ out,
    __bf16* __restrict__ Opart, float* __restrict__ lpart) {
  __shared__ __align__(16) __bf16 K_s[64 * 136];
  __shared__ __align__(16) __bf16 VT_s[128 * 72];

  const int t = threadIdx.x, w = t >> 6, lane = t & 63;
  const int quad = lane >> 4, l16 = lane & 15;
  const int b = blockIdx.x & 3;
  const int r = (AUNITS - 1) - (blockIdx.x >> 2);
  int tt = 0;
  while ((((tt + 2) * (tt + 2)) >> 2) <= r) ++tt;
  const int c = r - (((tt + 1) * (tt + 1)) >> 2);
  const int qrb = tt * 64;
  const int k0 = c * 128;
  const int kend = min(k0 + 128, qrb + 64);
  const int ntiles = (kend - k0) >> 6;
  const int qsb = qrb + w * 16;

  const size_t bq = (size_t)b * BPLANE;
  const __bf16* __restrict__ qp = qkv + bq;
  const __bf16* __restrict__ kp = qkv + PLANE + bq;
  const __bf16* __restrict__ vt = qkv + 2 * (size_t)PLANE + bq;

  bf16x8 qf[4];
#pragma unroll
  for (int cc = 0; cc < 4; ++cc)
    qf[cc] = *(const bf16x8*)&qp[(size_t)(qsb + l16) * HH + cc * 32 + quad * 8];

  f32x4 of[8];
#pragma unroll
  for (int f = 0; f < 8; ++f) of[f] = (f32x4){0.f, 0.f, 0.f, 0.f};
  float lp = 0.f;

  bf16x8 krg[4], vrg[4];
#pragma unroll
  for (int i = 0; i < 4; ++i) {
    const int idx = t + i * 256;
    const int row = idx >> 4, dc = (idx & 15) * 8;
    krg[i] = *(const bf16x8*)&kp[(size_t)(k0 + row) * HH + dc];
  }
#pragma unroll
  for (int i = 0; i < 4; ++i) {
    const int idx = t + i * 256;
    const int d = idx >> 3, kc = (idx & 7) * 8;
    vrg[i] = *(const bf16x8*)&vt[(size_t)d * SS + k0 + kc];
  }

  for (int jt = 0; jt < ntiles; ++jt) {
    __syncthreads();
#pragma unroll
    for (int i = 0; i < 4; ++i) {
      const int idx = t + i * 256;
      const int row = idx >> 4, dc = (idx & 15) * 8;
      const int lam = (row & 32) + ((row & 4) ? 16 : 0) +
                      (((row & 31) >> 3) << 2) + (row & 3);
      *(bf16x8*)&K_s[lam * 136 + dc] = krg[i];
    }
#pragma unroll
    for (int i = 0; i < 4; ++i) {
      const int idx = t + i * 256;
      const int d = idx >> 3, kc = (idx & 7) * 8;
      *(bf16x8*)&VT_s[d * 72 + kc] = vrg[i];
    }
    __syncthreads();

    if (jt + 1 < ntiles) {
      const int kb2 = k0 + (jt + 1) * 64;
#pragma unroll
      for (int i = 0; i < 4; ++i) {
        const int idx = t + i * 256;
        const int row = idx >> 4, dc = (idx & 15) * 8;
        krg[i] = *(const bf16x8*)&kp[(size_t)(kb2 + row) * HH + dc];
      }
#pragma unroll
      for (int i = 0; i < 4; ++i) {
        const int idx = t + i * 256;
        const int d = idx >> 3, kc = (idx & 7) * 8;
        vrg[i] = *(const bf16x8*)&vt[(size_t)d * SS + kb2 + kc];
      }
    }

#pragma unroll
    for (int s32 = 0; s32 < 2; ++s32) {
      const int kabs = k0 + jt * 64 + s32 * 32;
      if (kabs <= qsb + 15) {
        bf16x8 ku[4], kv[4];
#pragma unroll
        for (int cc = 0; cc < 4; ++cc) {
          ku[cc] = *(const bf16x8*)&K_s[(s32 * 32 + l16) * 136 + cc * 32 + quad * 8];
          kv[cc] = *(const bf16x8*)&K_s[(s32 * 32 + 16 + l16) * 136 + cc * 32 + quad * 8];
        }
        f32x4 su = (f32x4){0.f, 0.f, 0.f, 0.f};
        f32x4 sv = (f32x4){0.f, 0.f, 0.f, 0.f};
#pragma unroll
        for (int cc = 0; cc < 4; ++cc) {
          su = __builtin_amdgcn_mfma_f32_16x16x32_bf16(ku[cc], qf[cc], su, 0, 0, 0);
          sv = __builtin_amdgcn_mfma_f32_16x16x32_bf16(kv[cc], qf[cc], sv, 0, 0, 0);
        }
        const int qg = qsb + l16;
        bf16x8 pa;
#pragma unroll
        for (int rr = 0; rr < 4; ++rr) {
          const int kU = kabs + quad * 8 + rr;
          const float eU = (kU <= qg) ? exp2f(su[rr]) : 0.f;
          const float eV = (kU + 4 <= qg) ? exp2f(sv[rr]) : 0.f;
          pa[rr] = (__bf16)eU;
          pa[4 + rr] = (__bf16)eV;
          lp += eU + eV;
        }
#pragma unroll
        for (int f = 0; f < 8; ++f) {
          const bf16x8 vb =
              *(const bf16x8*)&VT_s[(f * 16 + l16) * 72 + s32 * 32 + quad * 8];
          of[f] = __builtin_amdgcn_mfma_f32_16x16x32_bf16(pa, vb, of[f], 0, 0, 0);
        }
      }
    }
  }

  lp += __shfl_xor(lp, 16);
  lp += __shfl_xor(lp, 32);

  if (tt < 2) {
#pragma unroll
    for (int rr = 0; rr < 4; ++rr) {
      const float lrow = __shfl(lp, quad * 4 + rr);
      const float inv = 1.0f / lrow;
#pragma unroll
      for (int f = 0; f < 8; ++f)
        out[bq + (size_t)(qsb + quad * 4 + rr) * HH + f * 16 + l16] =
            of[f][rr] * inv;
    }
  } else {
    const int u = b * AUNITS + r;
    __bf16* op = Opart + (size_t)u * 8192;
#pragma unroll
    for (int f = 0; f < 8; ++f)
#pragma unroll
      for (int rr = 0; rr < 4; ++rr)
        op[(w * 16 + quad * 4 + rr) * 128 + f * 16 + l16] = (__bf16)of[f][rr];
    if (quad == 0) lpart[u * 64 + w * 16 + l16] = lp;
  }
}

__global__ __launch_bounds__(256) void attn_merge(
    const __bf16* __restrict__ Opart, const float* __restrict__ lpart,
    float* __restrict__ out) {
  const int q4 = blockIdx.x & 3;
  const int m = blockIdx.x >> 2;  // 0..119
  const int b = m / 30;
  const int tile = 2 + (m % 30);
  const int nc = (tile + 2) >> 1;
  const int u0 = b * AUNITS + (((tile + 1) * (tile + 1)) >> 2);
  const int idx = q4 * 256 + threadIdx.x;
  const int e0 = idx * 8;
  const int row = idx >> 4;
  float acc[8] = {0.f, 0.f, 0.f, 0.f, 0.f, 0.f, 0.f, 0.f};
  float lsum = 0.f;
  for (int cc = 0; cc < nc; ++cc) {
    const bf16x8 pv = *(const bf16x8*)&Opart[(size_t)(u0 + cc) * 8192 + e0];
#pragma unroll
    for (int k = 0; k < 8; ++k) acc[k] += (float)pv[k];
    lsum += lpart[(u0 + cc) * 64 + row];
  }
  const float inv = 1.0f / lsum;
  float4 r0, r1;
  r0.x = acc[0] * inv; r0.y = acc[1] * inv; r0.z = acc[2] * inv; r0.w = acc[3] * inv;
  r1.x = acc[4] * inv; r1.y = acc[5] * inv; r1.z = acc[6] * inv; r1.w = acc[7] * inv;
  float* op = out + (size_t)b * BPLANE + (size_t)tile * 8192 + e0;
  ((float4*)op)[0] = r0;
  ((float4*)op)[1] = r1;
}

extern "C" void kernel_launch(void* const* d_in, const int* in_sizes, int n_in,
                              void* d_out, int out_size, void* d_ws, size_t ws_size,
                              hipStream_t stream) {
  const float* x  = (const float*)d_in[0];
  const float* Wq = (const float*)d_in[1];
  const float* Wk = (const float*)d_in[2];
  const float* Wv = (const float*)d_in[3];
  float* out = (float*)d_out;

  // ws: qkv bf16 6.29MB | WT 0.79MB | Opart (sized for fallback) 17.8MB | lpart
  char* wsb = (char*)d_ws;
  __bf16* qkv = (__bf16*)wsb;
  __bf16* WT = (__bf16*)(wsb + (size_t)3 * PLANE * 2);
  __bf16* Opart = (__bf16*)(wsb + (size_t)3 * PLANE * 2 + (size_t)3 * HH * EE * 2);
  float* lpart = (float*)(wsb + (size_t)3 * PLANE * 2 + (size_t)3 * HH * EE * 2 +
                          (size_t)BB * AUNITS * 8192 * 2);

  // Host-only queries (capture-safe): is a 512-block cooperative launch valid?
  int dev = 0;
  (void)hipGetDevice(&dev);
  int coop = 0, ncu = 0, maxb = 0;
  (void)hipDeviceGetAttribute(&coop, hipDeviceAttributeCooperativeLaunch, dev);
  (void)hipDeviceGetAttribute(&ncu, hipDeviceAttributeMultiprocessorCount, dev);
  (void)hipOccupancyMaxActiveBlocksPerMultiprocessor(&maxb, (const void*)fused_head,
                                                     256, 0);
  const bool use_coop = (coop != 0) && ((long)maxb * ncu >= NBLK_C);

  if (use_coop) {
    void* args[] = {(void*)&x, (void*)&Wq, (void*)&Wk, (void*)&Wv,
                    (void*)&qkv, (void*)&WT, (void*)&Opart, (void*)&lpart,
                    (void*)&out};
    hipLaunchCooperativeKernel((void*)fused_head, dim3(NBLK_C), dim3(256), args,
                               0, stream);
  } else {
    prep_w<<<384, 256, 0, stream>>>(Wq, Wk, Wv, WT);
    qkv_proj<<<dim3(BB * SS / 32, 3), 256, 0, stream>>>(x, WT, qkv);
    flash_attn_mfma<<<BB * AUNITS, 256, 0, stream>>>(qkv, out, Opart, lpart);
    attn_merge<<<BB * 30 * 4, 256, 0, stream>>>(Opart, lpart, out);
  }
}